// Round 1
// baseline (1221.027 us; speedup 1.0000x reference)
//
#include <hip/hip_runtime.h>
#include <cstdint>
#include <cstddef>

// ---------------------------------------------------------------------------
// TransformerMultiViewFusion (MI355X / gfx950), round 1.
//
//  tokens: t = pixel*4 + cam, pixel = (b*96+h)*96+w  -> 73728 tokens, E=256
//  pipeline per layer: qkv GEMM -> attention(S=4) -> Wo GEMM -> LN(resid)
//                      -> FFN1(relu) -> FFN2 -> LN(resid)
//  GEMMs: bf16 MFMA 16x16x32, 128x128 block tile, BK=64,
//         global_load_lds(16B) staging, XOR-swizzled LDS chunk layout.
//  Workspace (229,638,144 B):
//    X   @ 0          73728*256 bf16   (37,748,736)
//    QKV @ 37748736   73728*768 bf16   (113,246,208)
//    SA  @ 150994944  73728*256 bf16   (37,748,736)   [QKV∪SA aliased by H]
//    Y   @ 188743680  73728*256 bf16   (37,748,736)
//    Wb  @ 226492416  1572864   bf16   (3,145,728)
// ---------------------------------------------------------------------------

typedef __bf16 bf16;
typedef __bf16 bf16x8 __attribute__((ext_vector_type(8)));
typedef float  f32x4  __attribute__((ext_vector_type(4)));

__device__ __forceinline__ void async_copy16(const void* g, void* l)
{
    __builtin_amdgcn_global_load_lds(
        (__attribute__((address_space(1))) void*)g,
        (__attribute__((address_space(3))) void*)l,
        16, 0, 0);
}

// --------------------------------------------------------------------------
// fp32 -> bf16 pack
// --------------------------------------------------------------------------
__global__ void to_bf16_k(const float* __restrict__ src, bf16* __restrict__ dst, int n)
{
    int i = blockIdx.x * 256 + threadIdx.x;
    if (i < n) dst[i] = (bf16)src[i];
}

// --------------------------------------------------------------------------
// input projection: x[t][e] = sum_c features[cam][b][c][hw] * Wp[e][c] + bp[e]
// one block per token; 256 threads = 256 output channels.
// --------------------------------------------------------------------------
__global__ void input_proj_k(const float* __restrict__ feat,
                             const float* __restrict__ Wp,
                             const float* __restrict__ bp,
                             bf16* __restrict__ X)
{
    const int t   = blockIdx.x;
    const int tid = threadIdx.x;
    const int cam = t & 3;
    const int p   = t >> 2;
    const int b   = p / 9216;
    const int hw  = p % 9216;

    __shared__ float f[64];
    if (tid < 64)
        f[tid] = feat[((size_t)((cam * 2 + b) * 64 + tid)) * 9216 + hw];
    __syncthreads();

    float acc = bp[tid];
    const float* w = Wp + tid * 64;
#pragma unroll
    for (int c = 0; c < 64; ++c) acc += f[c] * w[c];
    X[(size_t)t * 256 + tid] = (bf16)acc;
}

// --------------------------------------------------------------------------
// GEMM-BT: C[M,N] = A[M,K] @ B[N,K]^T + bias[N]  (optional relu), bf16 in/out
// M = 73728 implicit via gridDim.y*128. N,K multiples of 128/64.
// 256 threads = 4 waves (2x2), each wave 64x64 out = 4x4 mfma_16x16x32_bf16.
// LDS: As/Bs 128 rows x 8 chunks(16B); chunk stored at position c^(row&7).
// --------------------------------------------------------------------------
template <bool RELU>
__global__ __launch_bounds__(256, 2) void gemm_bt(
    const bf16* __restrict__ A, const bf16* __restrict__ B,
    const float* __restrict__ bias, bf16* __restrict__ C,
    int N, int K)
{
    __shared__ __align__(16) bf16 As[128 * 64];
    __shared__ __align__(16) bf16 Bs[128 * 64];

    const int tid  = threadIdx.x;
    const int lane = tid & 63;
    const int wv   = tid >> 6;
    const int wm   = wv >> 1;
    const int wn   = wv & 1;
    const int bm   = blockIdx.y * 128;
    const int bn   = blockIdx.x * 128;

    // staging: wave wv covers rows [32wv,32wv+32), 4 insts x 8 rows each.
    const int r8  = lane >> 3;       // row within 8-row group
    const int p8  = lane & 7;        // physical chunk slot this lane fills
    const int gch = p8 ^ r8;         // global chunk to fetch (row&7 == r8)

    const int quad = lane >> 4;
    const int l16  = lane & 15;

    f32x4 acc[4][4] = {};

    for (int k0 = 0; k0 < K; k0 += 64) {
#pragma unroll
        for (int inst = 0; inst < 4; ++inst) {
            const int row = wv * 32 + inst * 8 + r8;
            const bf16* ga = A + (size_t)(bm + row) * K + (k0 + gch * 8);
            const bf16* gb = B + (size_t)(bn + row) * K + (k0 + gch * 8);
            async_copy16(ga, (char*)As + (wv * 4 + inst) * 1024);
            async_copy16(gb, (char*)Bs + (wv * 4 + inst) * 1024);
        }
        __syncthreads();   // drains vmcnt before barrier (compiler-enforced)

#pragma unroll
        for (int kk = 0; kk < 2; ++kk) {
            bf16x8 af[4], bfr[4];
            const int lch = kk * 4 + quad;   // logical 16B chunk within row
#pragma unroll
            for (int i = 0; i < 4; ++i) {
                const int m = wm * 64 + i * 16 + l16;
                af[i] = *(const bf16x8*)((const char*)As + (m * 8 + (lch ^ (m & 7))) * 16);
                const int n = wn * 64 + i * 16 + l16;
                bfr[i] = *(const bf16x8*)((const char*)Bs + (n * 8 + (lch ^ (n & 7))) * 16);
            }
#pragma unroll
            for (int i = 0; i < 4; ++i)
#pragma unroll
                for (int j = 0; j < 4; ++j)
                    acc[i][j] = __builtin_amdgcn_mfma_f32_16x16x32_bf16(
                        af[i], bfr[j], acc[i][j], 0, 0, 0);
        }
        __syncthreads();
    }

    // epilogue: D row = (lane>>4)*4 + reg (A's m), col = lane&15 (B's n)
#pragma unroll
    for (int j = 0; j < 4; ++j) {
        const int n = bn + wn * 64 + j * 16 + l16;
        const float bv = bias[n];
#pragma unroll
        for (int i = 0; i < 4; ++i) {
            const int mb = bm + wm * 64 + i * 16 + quad * 4;
#pragma unroll
            for (int r = 0; r < 4; ++r) {
                float v = acc[i][j][r] + bv;
                if (RELU) v = fmaxf(v, 0.f);
                C[(size_t)(mb + r) * N + n] = (bf16)v;
            }
        }
    }
}

// --------------------------------------------------------------------------
// attention: per sequence (4 tokens), 8 heads x dh=32, softmax over 4 keys.
// 4 waves/block, one wave per sequence. qkv rows = 4s..4s+3, 768 wide.
// --------------------------------------------------------------------------
__global__ __launch_bounds__(256) void attention_k(const bf16* __restrict__ QKV,
                                                   bf16* __restrict__ SA)
{
    __shared__ float qf[4][4][768];      // [wave][token][3E]
    __shared__ float sc[4][8][4][4];     // [wave][head][qi][kj]

    const int tid  = threadIdx.x;
    const int wv   = tid >> 6;
    const int lane = tid & 63;
    const int s    = blockIdx.x * 4 + wv;

    const bf16* base = QKV + (size_t)s * 4 * 768;
    for (int idx = lane; idx < 3072; idx += 64)
        qf[wv][idx / 768][idx % 768] = (float)base[idx];
    __syncthreads();

    // scores: 128 (h,i,j) per wave -> 2 per lane; lane-rotated dot to avoid
    // the h*32-stride bank degeneracy.
#pragma unroll
    for (int rep = 0; rep < 2; ++rep) {
        const int t = rep * 64 + lane;
        const int h = t >> 4, i = (t >> 2) & 3, j = t & 3;
        const float* q = &qf[wv][i][h * 32];
        const float* k = &qf[wv][j][256 + h * 32];
        float a = 0.f;
#pragma unroll
        for (int dd = 0; dd < 32; ++dd) {
            const int d = (dd + lane) & 31;
            a += q[d] * k[d];
        }
        sc[wv][h][i][j] = a * 0.17677669529663687f;   // 1/sqrt(32)
    }
    __syncthreads();

    if (lane < 32) {
        const int h = lane >> 2, i = lane & 3;
        float s0 = sc[wv][h][i][0], s1 = sc[wv][h][i][1];
        float s2 = sc[wv][h][i][2], s3 = sc[wv][h][i][3];
        float m = fmaxf(fmaxf(s0, s1), fmaxf(s2, s3));
        float e0 = expf(s0 - m), e1 = expf(s1 - m);
        float e2 = expf(s2 - m), e3 = expf(s3 - m);
        float inv = 1.f / (e0 + e1 + e2 + e3);
        sc[wv][h][i][0] = e0 * inv;
        sc[wv][h][i][1] = e1 * inv;
        sc[wv][h][i][2] = e2 * inv;
        sc[wv][h][i][3] = e3 * inv;
    }
    __syncthreads();

#pragma unroll
    for (int rep = 0; rep < 16; ++rep) {
        const int idx = rep * 64 + lane;          // 0..1023
        const int i = idx >> 8, col = idx & 255;
        const int h = col >> 5;
        float a = 0.f;
#pragma unroll
        for (int j = 0; j < 4; ++j)
            a += sc[wv][h][i][j] * qf[wv][j][512 + col];
        SA[(size_t)(s * 4 + i) * 256 + col] = (bf16)a;
    }
}

// --------------------------------------------------------------------------
// X = LayerNorm(X + Y) * g + b   (rowwise over 256), wave per row, in-place.
// --------------------------------------------------------------------------
__global__ __launch_bounds__(256) void ln_residual_k(const bf16* __restrict__ Xin,
                                                     const bf16* __restrict__ Y,
                                                     const float* __restrict__ g,
                                                     const float* __restrict__ b,
                                                     bf16* __restrict__ Xout)
{
    const int wv   = threadIdx.x >> 6;
    const int lane = threadIdx.x & 63;
    const size_t r = (size_t)blockIdx.x * 4 + wv;

    float v[4];
    float s = 0.f;
#pragma unroll
    for (int it = 0; it < 4; ++it) {
        const int e = it * 64 + lane;
        const float xv = (float)Xin[r * 256 + e] + (float)Y[r * 256 + e];
        v[it] = xv; s += xv;
    }
#pragma unroll
    for (int off = 32; off; off >>= 1) s += __shfl_xor(s, off, 64);
    const float mu = s * (1.f / 256.f);

    float s2 = 0.f;
#pragma unroll
    for (int it = 0; it < 4; ++it) { const float d = v[it] - mu; s2 += d * d; }
#pragma unroll
    for (int off = 32; off; off >>= 1) s2 += __shfl_xor(s2, off, 64);
    const float rstd = rsqrtf(s2 * (1.f / 256.f) + 1e-5f);

#pragma unroll
    for (int it = 0; it < 4; ++it) {
        const int e = it * 64 + lane;
        Xout[r * 256 + e] = (bf16)((v[it] - mu) * rstd * g[e] + b[e]);
    }
}

// --------------------------------------------------------------------------
// out[b][c][hw] = sum_e (mean_cam X[p*4+cam][e]) * Wout[c][e] + bout[c]
// block: 256 threads, 16 pixels.
// --------------------------------------------------------------------------
__global__ __launch_bounds__(256) void out_proj_k(const bf16* __restrict__ X,
                                                  const float* __restrict__ Wout,
                                                  const float* __restrict__ bout,
                                                  float* __restrict__ out)
{
    __shared__ float fused[16][260];   // +4 pad: kills 16-way bank conflict
    const int tid = threadIdx.x;
    const int p0  = blockIdx.x * 16;

#pragma unroll
    for (int it = 0; it < 16; ++it) {
        const int idx = it * 256 + tid;
        const int pix = idx >> 8, e = idx & 255;
        const size_t base = (size_t)(p0 + pix) * 1024 + e;
        const float s = (float)X[base] + (float)X[base + 256] +
                        (float)X[base + 512] + (float)X[base + 768];
        fused[pix][e] = s * 0.25f;
    }
    __syncthreads();

    const int pix = tid & 15;
    const int c0  = tid >> 4;
    const int p   = p0 + pix;
    const int b   = p / 9216;
    const int hw  = p % 9216;
#pragma unroll
    for (int it = 0; it < 4; ++it) {
        const int c = it * 16 + c0;
        const float* w = Wout + c * 256;
        float acc = bout[c];
#pragma unroll 8
        for (int e = 0; e < 256; ++e) acc += fused[pix][e] * w[e];
        out[((size_t)b * 64 + c) * 9216 + hw] = acc;
    }
}

// --------------------------------------------------------------------------
extern "C" void kernel_launch(void* const* d_in, const int* in_sizes, int n_in,
                              void* d_out, int out_size, void* d_ws, size_t ws_size,
                              hipStream_t stream)
{
    const float* features = (const float*)d_in[0];
    const float* Wp   = (const float*)d_in[1];
    const float* bp   = (const float*)d_in[2];
    const float* Wqkv = (const float*)d_in[3];
    const float* bqkv = (const float*)d_in[4];
    const float* Wo   = (const float*)d_in[5];
    const float* bo   = (const float*)d_in[6];
    const float* W1   = (const float*)d_in[7];
    const float* b1   = (const float*)d_in[8];
    const float* W2   = (const float*)d_in[9];
    const float* b2   = (const float*)d_in[10];
    const float* g1   = (const float*)d_in[11];
    const float* be1  = (const float*)d_in[12];
    const float* g2   = (const float*)d_in[13];
    const float* be2  = (const float*)d_in[14];
    const float* Wout = (const float*)d_in[15];
    const float* bout = (const float*)d_in[16];
    float* out = (float*)d_out;

    char* ws = (char*)d_ws;
    bf16* X   = (bf16*)(ws);                    // 73728*256
    bf16* QKV = (bf16*)(ws + 37748736ull);      // 73728*768
    bf16* SAb = (bf16*)(ws + 150994944ull);     // 73728*256
    bf16* Y   = (bf16*)(ws + 188743680ull);     // 73728*256
    bf16* Wb  = (bf16*)(ws + 226492416ull);     // packed bf16 weights
    bf16* H   = QKV;                            // FFN hidden aliases QKV∪SA

    bf16* WqkvB = Wb;                  // 2 x 768*256
    bf16* WoB   = Wb + 393216;         // 2 x 256*256
    bf16* W1B   = Wb + 524288;         // 2 x 1024*256
    bf16* W2B   = Wb + 1048576;        // 2 x 256*1024

    // pack weights to bf16 (ws is re-poisoned before every call)
    to_bf16_k<<<1536, 256, 0, stream>>>(Wqkv, WqkvB, 393216);
    to_bf16_k<<<512,  256, 0, stream>>>(Wo,   WoB,   131072);
    to_bf16_k<<<2048, 256, 0, stream>>>(W1,   W1B,   524288);
    to_bf16_k<<<2048, 256, 0, stream>>>(W2,   W2B,   524288);

    input_proj_k<<<73728, 256, 0, stream>>>(features, Wp, bp, X);

    for (int l = 0; l < 2; ++l) {
        gemm_bt<false><<<dim3(6, 576), 256, 0, stream>>>(
            X, WqkvB + l * 196608, bqkv + l * 768, QKV, 768, 256);
        attention_k<<<4608, 256, 0, stream>>>(QKV, SAb);
        gemm_bt<false><<<dim3(2, 576), 256, 0, stream>>>(
            SAb, WoB + l * 65536, bo + l * 256, Y, 256, 256);
        ln_residual_k<<<18432, 256, 0, stream>>>(X, Y, g1 + l * 256, be1 + l * 256, X);
        gemm_bt<true><<<dim3(8, 576), 256, 0, stream>>>(
            X, W1B + l * 262144, b1 + l * 1024, H, 1024, 256);
        gemm_bt<false><<<dim3(2, 576), 256, 0, stream>>>(
            H, W2B + l * 262144, b2 + l * 256, Y, 256, 1024);
        ln_residual_k<<<18432, 256, 0, stream>>>(X, Y, g2 + l * 256, be2 + l * 256, X);
    }

    out_proj_k<<<1152, 256, 0, stream>>>(X, Wout, bout, out);
}

// Round 2
// 786.308 us; speedup vs baseline: 1.5529x; 1.5529x over previous
//
#include <hip/hip_runtime.h>
#include <cstdint>
#include <cstddef>

// ---------------------------------------------------------------------------
// TransformerMultiViewFusion (MI355X / gfx950), round 2.
//
//  R2 change: input_proj_k rewritten from 73728 latency-bound micro-blocks
//  (559 us, 6.8% VALUBusy) to 1152 register-tiled blocks: LDS-staged
//  coalesced feature tile, 8pix x 8e register tile per thread, float4 Wp
//  reads from L1/L2, bf16x8 coalesced stores. Everything else unchanged.
//
//  Workspace (229,638,144 B):
//    X   @ 0          73728*256 bf16   (37,748,736)
//    QKV @ 37748736   73728*768 bf16   (113,246,208)
//    SA  @ 150994944  73728*256 bf16   (37,748,736)   [QKV∪SA aliased by H]
//    Y   @ 188743680  73728*256 bf16   (37,748,736)
//    Wb  @ 226492416  1572864   bf16   (3,145,728)
// ---------------------------------------------------------------------------

typedef __bf16 bf16;
typedef __bf16 bf16x8 __attribute__((ext_vector_type(8)));
typedef float  f32x4  __attribute__((ext_vector_type(4)));

__device__ __forceinline__ void async_copy16(const void* g, void* l)
{
    __builtin_amdgcn_global_load_lds(
        (__attribute__((address_space(1))) void*)g,
        (__attribute__((address_space(3))) void*)l,
        16, 0, 0);
}

// --------------------------------------------------------------------------
// fp32 -> bf16 pack
// --------------------------------------------------------------------------
__global__ void to_bf16_k(const float* __restrict__ src, bf16* __restrict__ dst, int n)
{
    int i = blockIdx.x * 256 + threadIdx.x;
    if (i < n) dst[i] = (bf16)src[i];
}

// --------------------------------------------------------------------------
// input projection: X[t][e] = sum_c feat[cam][b][c][hw] * Wp[e][c] + bp[e]
// grid = (144 hw-tiles of 64, 8 cam*b). Block: 64 pix x 256 e, K=64.
// LDS: f[c][pix] staged coalesced. Thread: 8 pix x 8 e register tile.
// Lane mapping: e-group = tid&31 (fast) -> coalesced bf16x8 stores;
//               pix-group = tid>>5.
// --------------------------------------------------------------------------
__global__ __launch_bounds__(256) void input_proj_k(const float* __restrict__ feat,
                                                    const float* __restrict__ Wp,
                                                    const float* __restrict__ bp,
                                                    bf16* __restrict__ X)
{
    __shared__ float fs[64][64];           // [c][pix], rows are 256B contiguous

    const int tid  = threadIdx.x;
    const int camb = blockIdx.y;           // cam*2 + b
    const int cam  = camb >> 1;
    const int b    = camb & 1;
    const int hw0  = blockIdx.x * 64;

    // stage 64c x 64pix, coalesced (each row = 64 consecutive floats)
    const float* fb = feat + (size_t)camb * 64 * 9216 + hw0;
#pragma unroll
    for (int rep = 0; rep < 16; ++rep) {
        const int idx = rep * 256 + tid;
        const int c = idx >> 6, p = idx & 63;
        fs[c][p] = fb[(size_t)c * 9216 + p];
    }
    __syncthreads();

    const int Eg = tid & 31;               // e-group: e = Eg*8 .. +7
    const int P  = tid >> 5;               // pix-group: pix = P*8 .. +7
    const int e0 = Eg * 8;

    float acc[8][8];                       // [pix_local][e_local]
    {
        const f32x4 b0 = *(const f32x4*)(bp + e0);
        const f32x4 b1 = *(const f32x4*)(bp + e0 + 4);
#pragma unroll
        for (int p = 0; p < 8; ++p)
#pragma unroll
            for (int i = 0; i < 4; ++i) { acc[p][i] = b0[i]; acc[p][4 + i] = b1[i]; }
    }

    for (int cc = 0; cc < 16; ++cc) {      // 4 c per chunk
        f32x4 wpf[8];
#pragma unroll
        for (int i = 0; i < 8; ++i)
            wpf[i] = *(const f32x4*)(Wp + (e0 + i) * 64 + cc * 4);
        f32x4 ffr[4][2];
#pragma unroll
        for (int c4 = 0; c4 < 4; ++c4)
#pragma unroll
            for (int j = 0; j < 2; ++j)
                ffr[c4][j] = *(const f32x4*)(&fs[cc * 4 + c4][P * 8 + j * 4]);
#pragma unroll
        for (int i = 0; i < 8; ++i)
#pragma unroll
            for (int c4 = 0; c4 < 4; ++c4)
#pragma unroll
                for (int j = 0; j < 2; ++j)
#pragma unroll
                    for (int q = 0; q < 4; ++q)
                        acc[j * 4 + q][i] += ffr[c4][j][q] * wpf[i][c4];
    }

    // write: token t = (b*9216 + hw0 + pix)*4 + cam, 8 e contiguous (16B)
    const int pbase = b * 9216 + hw0;
#pragma unroll
    for (int p = 0; p < 8; ++p) {
        const size_t t = (size_t)(pbase + P * 8 + p) * 4 + cam;
        bf16x8 v;
#pragma unroll
        for (int i = 0; i < 8; ++i) v[i] = (bf16)acc[p][i];
        *(bf16x8*)(X + t * 256 + e0) = v;
    }
}

// --------------------------------------------------------------------------
// GEMM-BT: C[M,N] = A[M,K] @ B[N,K]^T + bias[N]  (optional relu), bf16 in/out
// M = 73728 implicit via gridDim.y*128. N,K multiples of 128/64.
// 256 threads = 4 waves (2x2), each wave 64x64 out = 4x4 mfma_16x16x32_bf16.
// LDS: As/Bs 128 rows x 8 chunks(16B); chunk stored at position c^(row&7).
// --------------------------------------------------------------------------
template <bool RELU>
__global__ __launch_bounds__(256, 2) void gemm_bt(
    const bf16* __restrict__ A, const bf16* __restrict__ B,
    const float* __restrict__ bias, bf16* __restrict__ C,
    int N, int K)
{
    __shared__ __align__(16) bf16 As[128 * 64];
    __shared__ __align__(16) bf16 Bs[128 * 64];

    const int tid  = threadIdx.x;
    const int lane = tid & 63;
    const int wv   = tid >> 6;
    const int wm   = wv >> 1;
    const int wn   = wv & 1;
    const int bm   = blockIdx.y * 128;
    const int bn   = blockIdx.x * 128;

    // staging: wave wv covers rows [32wv,32wv+32), 4 insts x 8 rows each.
    const int r8  = lane >> 3;       // row within 8-row group
    const int p8  = lane & 7;        // physical chunk slot this lane fills
    const int gch = p8 ^ r8;         // global chunk to fetch (row&7 == r8)

    const int quad = lane >> 4;
    const int l16  = lane & 15;

    f32x4 acc[4][4] = {};

    for (int k0 = 0; k0 < K; k0 += 64) {
#pragma unroll
        for (int inst = 0; inst < 4; ++inst) {
            const int row = wv * 32 + inst * 8 + r8;
            const bf16* ga = A + (size_t)(bm + row) * K + (k0 + gch * 8);
            const bf16* gb = B + (size_t)(bn + row) * K + (k0 + gch * 8);
            async_copy16(ga, (char*)As + (wv * 4 + inst) * 1024);
            async_copy16(gb, (char*)Bs + (wv * 4 + inst) * 1024);
        }
        __syncthreads();   // drains vmcnt before barrier (compiler-enforced)

#pragma unroll
        for (int kk = 0; kk < 2; ++kk) {
            bf16x8 af[4], bfr[4];
            const int lch = kk * 4 + quad;   // logical 16B chunk within row
#pragma unroll
            for (int i = 0; i < 4; ++i) {
                const int m = wm * 64 + i * 16 + l16;
                af[i] = *(const bf16x8*)((const char*)As + (m * 8 + (lch ^ (m & 7))) * 16);
                const int n = wn * 64 + i * 16 + l16;
                bfr[i] = *(const bf16x8*)((const char*)Bs + (n * 8 + (lch ^ (n & 7))) * 16);
            }
#pragma unroll
            for (int i = 0; i < 4; ++i)
#pragma unroll
                for (int j = 0; j < 4; ++j)
                    acc[i][j] = __builtin_amdgcn_mfma_f32_16x16x32_bf16(
                        af[i], bfr[j], acc[i][j], 0, 0, 0);
        }
        __syncthreads();
    }

    // epilogue: D row = (lane>>4)*4 + reg (A's m), col = lane&15 (B's n)
#pragma unroll
    for (int j = 0; j < 4; ++j) {
        const int n = bn + wn * 64 + j * 16 + l16;
        const float bv = bias[n];
#pragma unroll
        for (int i = 0; i < 4; ++i) {
            const int mb = bm + wm * 64 + i * 16 + quad * 4;
#pragma unroll
            for (int r = 0; r < 4; ++r) {
                float v = acc[i][j][r] + bv;
                if (RELU) v = fmaxf(v, 0.f);
                C[(size_t)(mb + r) * N + n] = (bf16)v;
            }
        }
    }
}

// --------------------------------------------------------------------------
// attention: per sequence (4 tokens), 8 heads x dh=32, softmax over 4 keys.
// 4 waves/block, one wave per sequence. qkv rows = 4s..4s+3, 768 wide.
// --------------------------------------------------------------------------
__global__ __launch_bounds__(256) void attention_k(const bf16* __restrict__ QKV,
                                                   bf16* __restrict__ SA)
{
    __shared__ float qf[4][4][768];      // [wave][token][3E]
    __shared__ float sc[4][8][4][4];     // [wave][head][qi][kj]

    const int tid  = threadIdx.x;
    const int wv   = tid >> 6;
    const int lane = tid & 63;
    const int s    = blockIdx.x * 4 + wv;

    const bf16* base = QKV + (size_t)s * 4 * 768;
    for (int idx = lane; idx < 3072; idx += 64)
        qf[wv][idx / 768][idx % 768] = (float)base[idx];
    __syncthreads();

    // scores: 128 (h,i,j) per wave -> 2 per lane; lane-rotated dot to avoid
    // the h*32-stride bank degeneracy.
#pragma unroll
    for (int rep = 0; rep < 2; ++rep) {
        const int t = rep * 64 + lane;
        const int h = t >> 4, i = (t >> 2) & 3, j = t & 3;
        const float* q = &qf[wv][i][h * 32];
        const float* k = &qf[wv][j][256 + h * 32];
        float a = 0.f;
#pragma unroll
        for (int dd = 0; dd < 32; ++dd) {
            const int d = (dd + lane) & 31;
            a += q[d] * k[d];
        }
        sc[wv][h][i][j] = a * 0.17677669529663687f;   // 1/sqrt(32)
    }
    __syncthreads();

    if (lane < 32) {
        const int h = lane >> 2, i = lane & 3;
        float s0 = sc[wv][h][i][0], s1 = sc[wv][h][i][1];
        float s2 = sc[wv][h][i][2], s3 = sc[wv][h][i][3];
        float m = fmaxf(fmaxf(s0, s1), fmaxf(s2, s3));
        float e0 = expf(s0 - m), e1 = expf(s1 - m);
        float e2 = expf(s2 - m), e3 = expf(s3 - m);
        float inv = 1.f / (e0 + e1 + e2 + e3);
        sc[wv][h][i][0] = e0 * inv;
        sc[wv][h][i][1] = e1 * inv;
        sc[wv][h][i][2] = e2 * inv;
        sc[wv][h][i][3] = e3 * inv;
    }
    __syncthreads();

#pragma unroll
    for (int rep = 0; rep < 16; ++rep) {
        const int idx = rep * 64 + lane;          // 0..1023
        const int i = idx >> 8, col = idx & 255;
        const int h = col >> 5;
        float a = 0.f;
#pragma unroll
        for (int j = 0; j < 4; ++j)
            a += sc[wv][h][i][j] * qf[wv][j][512 + col];
        SA[(size_t)(s * 4 + i) * 256 + col] = (bf16)a;
    }
}

// --------------------------------------------------------------------------
// X = LayerNorm(X + Y) * g + b   (rowwise over 256), wave per row, in-place.
// --------------------------------------------------------------------------
__global__ __launch_bounds__(256) void ln_residual_k(const bf16* __restrict__ Xin,
                                                     const bf16* __restrict__ Y,
                                                     const float* __restrict__ g,
                                                     const float* __restrict__ b,
                                                     bf16* __restrict__ Xout)
{
    const int wv   = threadIdx.x >> 6;
    const int lane = threadIdx.x & 63;
    const size_t r = (size_t)blockIdx.x * 4 + wv;

    float v[4];
    float s = 0.f;
#pragma unroll
    for (int it = 0; it < 4; ++it) {
        const int e = it * 64 + lane;
        const float xv = (float)Xin[r * 256 + e] + (float)Y[r * 256 + e];
        v[it] = xv; s += xv;
    }
#pragma unroll
    for (int off = 32; off; off >>= 1) s += __shfl_xor(s, off, 64);
    const float mu = s * (1.f / 256.f);

    float s2 = 0.f;
#pragma unroll
    for (int it = 0; it < 4; ++it) { const float d = v[it] - mu; s2 += d * d; }
#pragma unroll
    for (int off = 32; off; off >>= 1) s2 += __shfl_xor(s2, off, 64);
    const float rstd = rsqrtf(s2 * (1.f / 256.f) + 1e-5f);

#pragma unroll
    for (int it = 0; it < 4; ++it) {
        const int e = it * 64 + lane;
        Xout[r * 256 + e] = (bf16)((v[it] - mu) * rstd * g[e] + b[e]);
    }
}

// --------------------------------------------------------------------------
// out[b][c][hw] = sum_e (mean_cam X[p*4+cam][e]) * Wout[c][e] + bout[c]
// block: 256 threads, 16 pixels.
// --------------------------------------------------------------------------
__global__ __launch_bounds__(256) void out_proj_k(const bf16* __restrict__ X,
                                                  const float* __restrict__ Wout,
                                                  const float* __restrict__ bout,
                                                  float* __restrict__ out)
{
    __shared__ float fused[16][260];   // +4 pad: kills 16-way bank conflict
    const int tid = threadIdx.x;
    const int p0  = blockIdx.x * 16;

#pragma unroll
    for (int it = 0; it < 16; ++it) {
        const int idx = it * 256 + tid;
        const int pix = idx >> 8, e = idx & 255;
        const size_t base = (size_t)(p0 + pix) * 1024 + e;
        const float s = (float)X[base] + (float)X[base + 256] +
                        (float)X[base + 512] + (float)X[base + 768];
        fused[pix][e] = s * 0.25f;
    }
    __syncthreads();

    const int pix = tid & 15;
    const int c0  = tid >> 4;
    const int p   = p0 + pix;
    const int b   = p / 9216;
    const int hw  = p % 9216;
#pragma unroll
    for (int it = 0; it < 4; ++it) {
        const int c = it * 16 + c0;
        const float* w = Wout + c * 256;
        float acc = bout[c];
#pragma unroll 8
        for (int e = 0; e < 256; ++e) acc += fused[pix][e] * w[e];
        out[((size_t)b * 64 + c) * 9216 + hw] = acc;
    }
}

// --------------------------------------------------------------------------
extern "C" void kernel_launch(void* const* d_in, const int* in_sizes, int n_in,
                              void* d_out, int out_size, void* d_ws, size_t ws_size,
                              hipStream_t stream)
{
    const float* features = (const float*)d_in[0];
    const float* Wp   = (const float*)d_in[1];
    const float* bp   = (const float*)d_in[2];
    const float* Wqkv = (const float*)d_in[3];
    const float* bqkv = (const float*)d_in[4];
    const float* Wo   = (const float*)d_in[5];
    const float* bo   = (const float*)d_in[6];
    const float* W1   = (const float*)d_in[7];
    const float* b1   = (const float*)d_in[8];
    const float* W2   = (const float*)d_in[9];
    const float* b2   = (const float*)d_in[10];
    const float* g1   = (const float*)d_in[11];
    const float* be1  = (const float*)d_in[12];
    const float* g2   = (const float*)d_in[13];
    const float* be2  = (const float*)d_in[14];
    const float* Wout = (const float*)d_in[15];
    const float* bout = (const float*)d_in[16];
    float* out = (float*)d_out;

    char* ws = (char*)d_ws;
    bf16* X   = (bf16*)(ws);                    // 73728*256
    bf16* QKV = (bf16*)(ws + 37748736ull);      // 73728*768
    bf16* SAb = (bf16*)(ws + 150994944ull);     // 73728*256
    bf16* Y   = (bf16*)(ws + 188743680ull);     // 73728*256
    bf16* Wb  = (bf16*)(ws + 226492416ull);     // packed bf16 weights
    bf16* H   = QKV;                            // FFN hidden aliases QKV∪SA

    bf16* WqkvB = Wb;                  // 2 x 768*256
    bf16* WoB   = Wb + 393216;         // 2 x 256*256
    bf16* W1B   = Wb + 524288;         // 2 x 1024*256
    bf16* W2B   = Wb + 1048576;        // 2 x 256*1024

    // pack weights to bf16 (ws is re-poisoned before every call)
    to_bf16_k<<<1536, 256, 0, stream>>>(Wqkv, WqkvB, 393216);
    to_bf16_k<<<512,  256, 0, stream>>>(Wo,   WoB,   131072);
    to_bf16_k<<<2048, 256, 0, stream>>>(W1,   W1B,   524288);
    to_bf16_k<<<2048, 256, 0, stream>>>(W2,   W2B,   524288);

    input_proj_k<<<dim3(144, 8), 256, 0, stream>>>(features, Wp, bp, X);

    for (int l = 0; l < 2; ++l) {
        gemm_bt<false><<<dim3(6, 576), 256, 0, stream>>>(
            X, WqkvB + l * 196608, bqkv + l * 768, QKV, 768, 256);
        attention_k<<<4608, 256, 0, stream>>>(QKV, SAb);
        gemm_bt<false><<<dim3(2, 576), 256, 0, stream>>>(
            SAb, WoB + l * 65536, bo + l * 256, Y, 256, 256);
        ln_residual_k<<<18432, 256, 0, stream>>>(X, Y, g1 + l * 256, be1 + l * 256, X);
        gemm_bt<true><<<dim3(8, 576), 256, 0, stream>>>(
            X, W1B + l * 262144, b1 + l * 1024, H, 1024, 256);
        gemm_bt<false><<<dim3(2, 576), 256, 0, stream>>>(
            H, W2B + l * 262144, b2 + l * 256, Y, 256, 1024);
        ln_residual_k<<<18432, 256, 0, stream>>>(X, Y, g2 + l * 256, be2 + l * 256, X);
    }

    out_proj_k<<<1152, 256, 0, stream>>>(X, Wout, bout, out);
}

// Round 3
// 761.677 us; speedup vs baseline: 1.6031x; 1.0323x over previous
//
#include <hip/hip_runtime.h>
#include <cstdint>
#include <cstddef>

// ---------------------------------------------------------------------------
// TransformerMultiViewFusion (MI355X / gfx950), round 3.
//
//  R3 changes:
//   * input_proj_k: __launch_bounds__(256,2) — R2's VGPR=60 showed the
//     compiler spilled the 8x8 acc tile to scratch (VALUBusy 22%). Cap 256.
//   * gemm_ln_k: Wo-GEMM and FFN2-GEMM now fuse bias+residual+LayerNorm in
//     the epilogue (64x256 tile = full rows -> block-local LN, cross-wave
//     reduce via shfl + 2KB LDS). Removes 4 ln_residual dispatches and the
//     Y buffer round-trip (~450MB).
//   * single pack_all_k for the 4 weight->bf16 packs.
//
//  Workspace:
//    X   @ 0          73728*256 bf16   (37,748,736)
//    QKV @ 37748736   73728*768 bf16   (113,246,208)  [H aliases QKV]
//    SA  @ 150994944  73728*256 bf16   (37,748,736)
//    Wb  @ 226492416  1572864   bf16   (3,145,728)
// ---------------------------------------------------------------------------

typedef __bf16 bf16;
typedef __bf16 bf16x8 __attribute__((ext_vector_type(8)));
typedef float  f32x4  __attribute__((ext_vector_type(4)));

__device__ __forceinline__ void async_copy16(const void* g, void* l)
{
    __builtin_amdgcn_global_load_lds(
        (__attribute__((address_space(1))) void*)g,
        (__attribute__((address_space(3))) void*)l,
        16, 0, 0);
}

// --------------------------------------------------------------------------
// all 4 weight packs in one launch. 1572864 = 6144*256 exactly.
// --------------------------------------------------------------------------
__global__ void pack_all_k(const float* __restrict__ s0, const float* __restrict__ s1,
                           const float* __restrict__ s2, const float* __restrict__ s3,
                           bf16* __restrict__ d0, bf16* __restrict__ d1,
                           bf16* __restrict__ d2, bf16* __restrict__ d3)
{
    const int i = blockIdx.x * 256 + threadIdx.x;
    if (i < 393216)       d0[i] = (bf16)s0[i];
    else if (i < 524288)  d1[i - 393216] = (bf16)s1[i - 393216];
    else if (i < 1048576) d2[i - 524288] = (bf16)s2[i - 524288];
    else                  d3[i - 1048576] = (bf16)s3[i - 1048576];
}

// --------------------------------------------------------------------------
// input projection: X[t][e] = sum_c feat[cam][b][c][hw] * Wp[e][c] + bp[e]
// grid = (144 hw-tiles of 64, 8 cam*b). Thread: 8pix x 8e register tile.
// (256,2): VGPR cap 256 — without it the compiler spilled acc (R2: VGPR=60).
// --------------------------------------------------------------------------
__global__ __launch_bounds__(256, 2) void input_proj_k(const float* __restrict__ feat,
                                                       const float* __restrict__ Wp,
                                                       const float* __restrict__ bp,
                                                       bf16* __restrict__ X)
{
    __shared__ float fs[64][64];           // [c][pix]

    const int tid  = threadIdx.x;
    const int camb = blockIdx.y;           // cam*2 + b
    const int cam  = camb >> 1;
    const int b    = camb & 1;
    const int hw0  = blockIdx.x * 64;

    const float* fb = feat + (size_t)camb * 64 * 9216 + hw0;
#pragma unroll
    for (int rep = 0; rep < 16; ++rep) {
        const int idx = rep * 256 + tid;
        const int c = idx >> 6, p = idx & 63;
        fs[c][p] = fb[(size_t)c * 9216 + p];
    }
    __syncthreads();

    const int Eg = tid & 31;               // e = Eg*8 .. +7
    const int P  = tid >> 5;               // pix = P*8 .. +7
    const int e0 = Eg * 8;

    float acc[8][8];
    {
        const f32x4 b0 = *(const f32x4*)(bp + e0);
        const f32x4 b1 = *(const f32x4*)(bp + e0 + 4);
#pragma unroll
        for (int p = 0; p < 8; ++p)
#pragma unroll
            for (int i = 0; i < 4; ++i) { acc[p][i] = b0[i]; acc[p][4 + i] = b1[i]; }
    }

    for (int cc = 0; cc < 16; ++cc) {
        f32x4 wpf[8];
#pragma unroll
        for (int i = 0; i < 8; ++i)
            wpf[i] = *(const f32x4*)(Wp + (e0 + i) * 64 + cc * 4);
        f32x4 ffr[4][2];
#pragma unroll
        for (int c4 = 0; c4 < 4; ++c4)
#pragma unroll
            for (int j = 0; j < 2; ++j)
                ffr[c4][j] = *(const f32x4*)(&fs[cc * 4 + c4][P * 8 + j * 4]);
#pragma unroll
        for (int i = 0; i < 8; ++i)
#pragma unroll
            for (int c4 = 0; c4 < 4; ++c4)
#pragma unroll
                for (int j = 0; j < 2; ++j)
#pragma unroll
                    for (int q = 0; q < 4; ++q)
                        acc[j * 4 + q][i] += ffr[c4][j][q] * wpf[i][c4];
    }

    const int pbase = b * 9216 + hw0;
#pragma unroll
    for (int p = 0; p < 8; ++p) {
        const size_t t = (size_t)(pbase + P * 8 + p) * 4 + cam;
        bf16x8 v;
#pragma unroll
        for (int i = 0; i < 8; ++i) v[i] = (bf16)acc[p][i];
        *(bf16x8*)(X + t * 256 + e0) = v;
    }
}

// --------------------------------------------------------------------------
// GEMM-BT: C[M,N] = A[M,K] @ B[N,K]^T + bias[N]  (optional relu), bf16 in/out
// 128x128 tile, 4 waves 2x2, XOR-swizzled LDS, global_load_lds(16B).
// --------------------------------------------------------------------------
template <bool RELU>
__global__ __launch_bounds__(256, 2) void gemm_bt(
    const bf16* __restrict__ A, const bf16* __restrict__ B,
    const float* __restrict__ bias, bf16* __restrict__ C,
    int N, int K)
{
    __shared__ __align__(16) bf16 As[128 * 64];
    __shared__ __align__(16) bf16 Bs[128 * 64];

    const int tid  = threadIdx.x;
    const int lane = tid & 63;
    const int wv   = tid >> 6;
    const int wm   = wv >> 1;
    const int wn   = wv & 1;
    const int bm   = blockIdx.y * 128;
    const int bn   = blockIdx.x * 128;

    const int r8  = lane >> 3;
    const int p8  = lane & 7;
    const int gch = p8 ^ r8;

    const int quad = lane >> 4;
    const int l16  = lane & 15;

    f32x4 acc[4][4] = {};

    for (int k0 = 0; k0 < K; k0 += 64) {
#pragma unroll
        for (int inst = 0; inst < 4; ++inst) {
            const int row = wv * 32 + inst * 8 + r8;
            const bf16* ga = A + (size_t)(bm + row) * K + (k0 + gch * 8);
            const bf16* gb = B + (size_t)(bn + row) * K + (k0 + gch * 8);
            async_copy16(ga, (char*)As + (wv * 4 + inst) * 1024);
            async_copy16(gb, (char*)Bs + (wv * 4 + inst) * 1024);
        }
        __syncthreads();

#pragma unroll
        for (int kk = 0; kk < 2; ++kk) {
            bf16x8 af[4], bfr[4];
            const int lch = kk * 4 + quad;
#pragma unroll
            for (int i = 0; i < 4; ++i) {
                const int m = wm * 64 + i * 16 + l16;
                af[i] = *(const bf16x8*)((const char*)As + (m * 8 + (lch ^ (m & 7))) * 16);
                const int n = wn * 64 + i * 16 + l16;
                bfr[i] = *(const bf16x8*)((const char*)Bs + (n * 8 + (lch ^ (n & 7))) * 16);
            }
#pragma unroll
            for (int i = 0; i < 4; ++i)
#pragma unroll
                for (int j = 0; j < 4; ++j)
                    acc[i][j] = __builtin_amdgcn_mfma_f32_16x16x32_bf16(
                        af[i], bfr[j], acc[i][j], 0, 0, 0);
        }
        __syncthreads();
    }

#pragma unroll
    for (int j = 0; j < 4; ++j) {
        const int n = bn + wn * 64 + j * 16 + l16;
        const float bv = bias[n];
#pragma unroll
        for (int i = 0; i < 4; ++i) {
            const int mb = bm + wm * 64 + i * 16 + quad * 4;
#pragma unroll
            for (int r = 0; r < 4; ++r) {
                float v = acc[i][j][r] + bv;
                if (RELU) v = fmaxf(v, 0.f);
                C[(size_t)(mb + r) * N + n] = (bf16)v;
            }
        }
    }
}

// --------------------------------------------------------------------------
// GEMM-BT + bias + residual + LayerNorm fused.  N = 256 (full row in-block).
// Xout = LN(A@B^T + bias + Xres) * gam + bet.   64x256 tile, 4 waves (1x4).
// LDS: S = As(64x64) | Bs(256x64), XOR-swizzled; red[64][4] for row sums.
// In-place Xres==Xout safe: block touches only its own 64 rows.
// --------------------------------------------------------------------------
__global__ __launch_bounds__(256, 2) void gemm_ln_k(
    const bf16* __restrict__ A, const bf16* __restrict__ B,
    const float* __restrict__ bias, const bf16* __restrict__ Xres,
    const float* __restrict__ gam, const float* __restrict__ bet,
    bf16* __restrict__ Xout, int K)
{
    __shared__ __align__(16) bf16 S[20480];   // 40KB: As @0 (4096), Bs @4096
    __shared__ float2 red[64][4];

    const int tid  = threadIdx.x;
    const int lane = tid & 63;
    const int wn   = tid >> 6;        // n-wave 0..3
    const int bm   = blockIdx.x * 64;
    const int quad = lane >> 4;
    const int l16  = lane & 15;

    f32x4 acc[4][4] = {};

    for (int k0 = 0; k0 < K; k0 += 64) {
#pragma unroll
        for (int s = 0; s < 10; ++s) {
            const int L   = s * 256 + tid;     // 0..2559: rows 0..319
            const int row = L >> 3;
            const int gch = (L & 7) ^ (row & 7);
            const bf16* g = (row < 64)
                ? A + (size_t)(bm + row) * K + (k0 + gch * 8)
                : B + (size_t)(row - 64) * K + (k0 + gch * 8);
            async_copy16(g, (char*)S + (size_t)L * 16);
        }
        __syncthreads();

#pragma unroll
        for (int kk = 0; kk < 2; ++kk) {
            const int lch = kk * 4 + quad;
            bf16x8 af[4], bfr[4];
#pragma unroll
            for (int i = 0; i < 4; ++i) {
                const int m = i * 16 + l16;
                af[i] = *(const bf16x8*)((const char*)S + (m * 8 + (lch ^ (m & 7))) * 16);
                const int n = wn * 64 + i * 16 + l16;
                bfr[i] = *(const bf16x8*)((const char*)S + ((64 + n) * 8 + (lch ^ (n & 7))) * 16);
            }
#pragma unroll
            for (int i = 0; i < 4; ++i)
#pragma unroll
                for (int j = 0; j < 4; ++j)
                    acc[i][j] = __builtin_amdgcn_mfma_f32_16x16x32_bf16(
                        af[i], bfr[j], acc[i][j], 0, 0, 0);
        }
        __syncthreads();
    }

    float bv[4], gv[4], bev[4];
#pragma unroll
    for (int j = 0; j < 4; ++j) {
        const int n = wn * 64 + j * 16 + l16;
        bv[j] = bias[n]; gv[j] = gam[n]; bev[j] = bet[n];
    }

    // v = acc + bias + resid; per-row partial sums over this wave's 64 cols
#pragma unroll
    for (int i = 0; i < 4; ++i) {
#pragma unroll
        for (int r = 0; r < 4; ++r) {
            const int rl  = i * 16 + quad * 4 + r;
            const size_t row = (size_t)(bm + rl);
            float s1 = 0.f, s2 = 0.f;
#pragma unroll
            for (int j = 0; j < 4; ++j) {
                const int n = wn * 64 + j * 16 + l16;
                const float v = acc[i][j][r] + bv[j] + (float)Xres[row * 256 + n];
                acc[i][j][r] = v;
                s1 += v; s2 += v * v;
            }
#pragma unroll
            for (int off = 1; off < 16; off <<= 1) {
                s1 += __shfl_xor(s1, off, 64);
                s2 += __shfl_xor(s2, off, 64);
            }
            if (l16 == 0) red[rl][wn] = make_float2(s1, s2);
        }
    }
    __syncthreads();

#pragma unroll
    for (int i = 0; i < 4; ++i) {
#pragma unroll
        for (int r = 0; r < 4; ++r) {
            const int rl = i * 16 + quad * 4 + r;
            const float2 p0 = red[rl][0], p1 = red[rl][1];
            const float2 p2 = red[rl][2], p3 = red[rl][3];
            const float mu  = (p0.x + p1.x + p2.x + p3.x) * (1.f / 256.f);
            const float ex2 = (p0.y + p1.y + p2.y + p3.y) * (1.f / 256.f);
            const float rstd = rsqrtf(fmaxf(ex2 - mu * mu, 0.f) + 1e-5f);
            const size_t row = (size_t)(bm + rl);
#pragma unroll
            for (int j = 0; j < 4; ++j) {
                const int n = wn * 64 + j * 16 + l16;
                Xout[row * 256 + n] = (bf16)((acc[i][j][r] - mu) * rstd * gv[j] + bev[j]);
            }
        }
    }
}

// --------------------------------------------------------------------------
// attention: per sequence (4 tokens), 8 heads x dh=32, softmax over 4 keys.
// --------------------------------------------------------------------------
__global__ __launch_bounds__(256) void attention_k(const bf16* __restrict__ QKV,
                                                   bf16* __restrict__ SA)
{
    __shared__ float qf[4][4][768];
    __shared__ float sc[4][8][4][4];

    const int tid  = threadIdx.x;
    const int wv   = tid >> 6;
    const int lane = tid & 63;
    const int s    = blockIdx.x * 4 + wv;

    const bf16* base = QKV + (size_t)s * 4 * 768;
    for (int idx = lane; idx < 3072; idx += 64)
        qf[wv][idx / 768][idx % 768] = (float)base[idx];
    __syncthreads();

#pragma unroll
    for (int rep = 0; rep < 2; ++rep) {
        const int t = rep * 64 + lane;
        const int h = t >> 4, i = (t >> 2) & 3, j = t & 3;
        const float* q = &qf[wv][i][h * 32];
        const float* k = &qf[wv][j][256 + h * 32];
        float a = 0.f;
#pragma unroll
        for (int dd = 0; dd < 32; ++dd) {
            const int d = (dd + lane) & 31;
            a += q[d] * k[d];
        }
        sc[wv][h][i][j] = a * 0.17677669529663687f;
    }
    __syncthreads();

    if (lane < 32) {
        const int h = lane >> 2, i = lane & 3;
        float s0 = sc[wv][h][i][0], s1 = sc[wv][h][i][1];
        float s2 = sc[wv][h][i][2], s3 = sc[wv][h][i][3];
        float m = fmaxf(fmaxf(s0, s1), fmaxf(s2, s3));
        float e0 = expf(s0 - m), e1 = expf(s1 - m);
        float e2 = expf(s2 - m), e3 = expf(s3 - m);
        float inv = 1.f / (e0 + e1 + e2 + e3);
        sc[wv][h][i][0] = e0 * inv;
        sc[wv][h][i][1] = e1 * inv;
        sc[wv][h][i][2] = e2 * inv;
        sc[wv][h][i][3] = e3 * inv;
    }
    __syncthreads();

#pragma unroll
    for (int rep = 0; rep < 16; ++rep) {
        const int idx = rep * 64 + lane;
        const int i = idx >> 8, col = idx & 255;
        const int h = col >> 5;
        float a = 0.f;
#pragma unroll
        for (int j = 0; j < 4; ++j)
            a += sc[wv][h][i][j] * qf[wv][j][512 + col];
        SA[(size_t)(s * 4 + i) * 256 + col] = (bf16)a;
    }
}

// --------------------------------------------------------------------------
// out[b][c][hw] = sum_e (mean_cam X[p*4+cam][e]) * Wout[c][e] + bout[c]
// --------------------------------------------------------------------------
__global__ __launch_bounds__(256) void out_proj_k(const bf16* __restrict__ X,
                                                  const float* __restrict__ Wout,
                                                  const float* __restrict__ bout,
                                                  float* __restrict__ out)
{
    __shared__ float fused[16][260];
    const int tid = threadIdx.x;
    const int p0  = blockIdx.x * 16;

#pragma unroll
    for (int it = 0; it < 16; ++it) {
        const int idx = it * 256 + tid;
        const int pix = idx >> 8, e = idx & 255;
        const size_t base = (size_t)(p0 + pix) * 1024 + e;
        const float s = (float)X[base] + (float)X[base + 256] +
                        (float)X[base + 512] + (float)X[base + 768];
        fused[pix][e] = s * 0.25f;
    }
    __syncthreads();

    const int pix = tid & 15;
    const int c0  = tid >> 4;
    const int p   = p0 + pix;
    const int b   = p / 9216;
    const int hw  = p % 9216;
#pragma unroll
    for (int it = 0; it < 4; ++it) {
        const int c = it * 16 + c0;
        const float* w = Wout + c * 256;
        float acc = bout[c];
#pragma unroll 8
        for (int e = 0; e < 256; ++e) acc += fused[pix][e] * w[e];
        out[((size_t)b * 64 + c) * 9216 + hw] = acc;
    }
}

// --------------------------------------------------------------------------
extern "C" void kernel_launch(void* const* d_in, const int* in_sizes, int n_in,
                              void* d_out, int out_size, void* d_ws, size_t ws_size,
                              hipStream_t stream)
{
    const float* features = (const float*)d_in[0];
    const float* Wp   = (const float*)d_in[1];
    const float* bp   = (const float*)d_in[2];
    const float* Wqkv = (const float*)d_in[3];
    const float* bqkv = (const float*)d_in[4];
    const float* Wo   = (const float*)d_in[5];
    const float* bo   = (const float*)d_in[6];
    const float* W1   = (const float*)d_in[7];
    const float* b1   = (const float*)d_in[8];
    const float* W2   = (const float*)d_in[9];
    const float* b2   = (const float*)d_in[10];
    const float* g1   = (const float*)d_in[11];
    const float* be1  = (const float*)d_in[12];
    const float* g2   = (const float*)d_in[13];
    const float* be2  = (const float*)d_in[14];
    const float* Wout = (const float*)d_in[15];
    const float* bout = (const float*)d_in[16];
    float* out = (float*)d_out;

    char* ws = (char*)d_ws;
    bf16* X   = (bf16*)(ws);                    // 73728*256
    bf16* QKV = (bf16*)(ws + 37748736ull);      // 73728*768
    bf16* SAb = (bf16*)(ws + 150994944ull);     // 73728*256
    bf16* Wb  = (bf16*)(ws + 226492416ull);     // packed bf16 weights
    bf16* H   = QKV;                            // FFN hidden aliases QKV

    bf16* WqkvB = Wb;                  // 2 x 768*256
    bf16* WoB   = Wb + 393216;         // 2 x 256*256
    bf16* W1B   = Wb + 524288;         // 2 x 1024*256
    bf16* W2B   = Wb + 1048576;        // 2 x 256*1024

    pack_all_k<<<6144, 256, 0, stream>>>(Wqkv, Wo, W1, W2, WqkvB, WoB, W1B, W2B);

    input_proj_k<<<dim3(144, 8), 256, 0, stream>>>(features, Wp, bp, X);

    for (int l = 0; l < 2; ++l) {
        gemm_bt<false><<<dim3(6, 576), 256, 0, stream>>>(
            X, WqkvB + l * 196608, bqkv + l * 768, QKV, 768, 256);
        attention_k<<<4608, 256, 0, stream>>>(QKV, SAb);
        gemm_ln_k<<<1152, 256, 0, stream>>>(
            SAb, WoB + l * 65536, bo + l * 256, X,
            g1 + l * 256, be1 + l * 256, X, 256);
        gemm_bt<true><<<dim3(8, 576), 256, 0, stream>>>(
            X, W1B + l * 262144, b1 + l * 1024, H, 1024, 256);
        gemm_ln_k<<<1152, 256, 0, stream>>>(
            H, W2B + l * 262144, b2 + l * 256, X,
            g2 + l * 256, be2 + l * 256, X, 1024);
    }

    out_proj_k<<<1152, 256, 0, stream>>>(X, Wout, bout, out);
}

// Round 4
// 757.840 us; speedup vs baseline: 1.6112x; 1.0051x over previous
//
#include <hip/hip_runtime.h>
#include <cstdint>
#include <cstddef>

// ---------------------------------------------------------------------------
// TransformerMultiViewFusion (MI355X / gfx950), round 4.
//
//  R4 changes:
//   * input projection rerouted through MFMA: feat_pack_k (streaming
//     transpose fp32->bf16 into Xf[t][c]) + gemm_bt K=64. Replaces the
//     VALU input_proj_k (90 us, compiler kept spilling the reg tile).
//   * gemm_ln_k: 64x256 -> 128x256 tile (waves 2x2, acc[4][8]); staging:MFMA
//     12:64 per k-chunk vs 10:32; grid 1152->576.
//   * pack_all_k also packs Wp.
//
//  Workspace:
//    X   @ 0          73728*256 bf16   (37,748,736)
//    QKV @ 37748736   73728*768 bf16   (113,246,208)  [H aliases QKV]
//    SA  @ 150994944  73728*256 bf16   (37,748,736)
//    Xf  @ 188743680  73728*64  bf16   (9,437,184)
//    WpB @ 198180864  16384     bf16   (32,768)
//    Wb  @ 226492416  1572864   bf16   (3,145,728)
// ---------------------------------------------------------------------------

typedef __bf16 bf16;
typedef __bf16 bf16x8 __attribute__((ext_vector_type(8)));
typedef float  f32x4  __attribute__((ext_vector_type(4)));

__device__ __forceinline__ void async_copy16(const void* g, void* l)
{
    __builtin_amdgcn_global_load_lds(
        (__attribute__((address_space(1))) void*)g,
        (__attribute__((address_space(3))) void*)l,
        16, 0, 0);
}

// --------------------------------------------------------------------------
// all 5 weight packs in one launch. 1589248 = 6208*256 exactly.
// --------------------------------------------------------------------------
__global__ void pack_all_k(const float* __restrict__ s0, const float* __restrict__ s1,
                           const float* __restrict__ s2, const float* __restrict__ s3,
                           const float* __restrict__ s4,
                           bf16* __restrict__ d0, bf16* __restrict__ d1,
                           bf16* __restrict__ d2, bf16* __restrict__ d3,
                           bf16* __restrict__ d4)
{
    const int i = blockIdx.x * 256 + threadIdx.x;
    if (i < 393216)       d0[i] = (bf16)s0[i];
    else if (i < 524288)  d1[i - 393216] = (bf16)s1[i - 393216];
    else if (i < 1048576) d2[i - 524288] = (bf16)s2[i - 524288];
    else if (i < 1572864) d3[i - 1048576] = (bf16)s3[i - 1048576];
    else                  d4[i - 1572864] = (bf16)s4[i - 1572864];
}

// --------------------------------------------------------------------------
// feat transpose-pack: Xf[t][c] = (bf16)feat[cam][b][c][hw]
// t = (b*9216+hw)*4+cam. grid (144 hw-tiles, 8 camb). Pure streaming.
// --------------------------------------------------------------------------
__global__ __launch_bounds__(256) void feat_pack_k(const float* __restrict__ feat,
                                                   bf16* __restrict__ Xf)
{
    __shared__ float ft[64][68];          // [hw][c], +4 pad (16B-aligned rows)

    const int tid  = threadIdx.x;
    const int camb = blockIdx.y;
    const int cam  = camb >> 1;
    const int b    = camb & 1;
    const int hw0  = blockIdx.x * 64;

    const float* fb = feat + (size_t)camb * 64 * 9216 + hw0;
#pragma unroll
    for (int rep = 0; rep < 16; ++rep) {
        const int idx = rep * 256 + tid;
        const int c = idx >> 6, p = idx & 63;
        ft[p][c] = fb[(size_t)c * 9216 + p];
    }
    __syncthreads();

    const int pbase = b * 9216 + hw0;
#pragma unroll
    for (int rep = 0; rep < 2; ++rep) {
        const int idx = rep * 256 + tid;   // 0..511
        const int p = idx >> 3, cc = idx & 7;
        const f32x4 a = *(const f32x4*)(&ft[p][cc * 8]);
        const f32x4 c4 = *(const f32x4*)(&ft[p][cc * 8 + 4]);
        bf16x8 v;
#pragma unroll
        for (int i = 0; i < 4; ++i) { v[i] = (bf16)a[i]; v[4 + i] = (bf16)c4[i]; }
        const size_t t = (size_t)(pbase + p) * 4 + cam;
        *(bf16x8*)(Xf + t * 64 + cc * 8) = v;
    }
}

// --------------------------------------------------------------------------
// GEMM-BT: C[M,N] = A[M,K] @ B[N,K]^T + bias[N]  (optional relu), bf16 in/out
// 128x128 tile, 4 waves 2x2, XOR-swizzled LDS, global_load_lds(16B).
// --------------------------------------------------------------------------
template <bool RELU>
__global__ __launch_bounds__(256, 2) void gemm_bt(
    const bf16* __restrict__ A, const bf16* __restrict__ B,
    const float* __restrict__ bias, bf16* __restrict__ C,
    int N, int K)
{
    __shared__ __align__(16) bf16 As[128 * 64];
    __shared__ __align__(16) bf16 Bs[128 * 64];

    const int tid  = threadIdx.x;
    const int lane = tid & 63;
    const int wv   = tid >> 6;
    const int wm   = wv >> 1;
    const int wn   = wv & 1;
    const int bm   = blockIdx.y * 128;
    const int bn   = blockIdx.x * 128;

    const int r8  = lane >> 3;
    const int p8  = lane & 7;
    const int gch = p8 ^ r8;

    const int quad = lane >> 4;
    const int l16  = lane & 15;

    f32x4 acc[4][4] = {};

    for (int k0 = 0; k0 < K; k0 += 64) {
#pragma unroll
        for (int inst = 0; inst < 4; ++inst) {
            const int row = wv * 32 + inst * 8 + r8;
            const bf16* ga = A + (size_t)(bm + row) * K + (k0 + gch * 8);
            const bf16* gb = B + (size_t)(bn + row) * K + (k0 + gch * 8);
            async_copy16(ga, (char*)As + (wv * 4 + inst) * 1024);
            async_copy16(gb, (char*)Bs + (wv * 4 + inst) * 1024);
        }
        __syncthreads();

#pragma unroll
        for (int kk = 0; kk < 2; ++kk) {
            bf16x8 af[4], bfr[4];
            const int lch = kk * 4 + quad;
#pragma unroll
            for (int i = 0; i < 4; ++i) {
                const int m = wm * 64 + i * 16 + l16;
                af[i] = *(const bf16x8*)((const char*)As + (m * 8 + (lch ^ (m & 7))) * 16);
                const int n = wn * 64 + i * 16 + l16;
                bfr[i] = *(const bf16x8*)((const char*)Bs + (n * 8 + (lch ^ (n & 7))) * 16);
            }
#pragma unroll
            for (int i = 0; i < 4; ++i)
#pragma unroll
                for (int j = 0; j < 4; ++j)
                    acc[i][j] = __builtin_amdgcn_mfma_f32_16x16x32_bf16(
                        af[i], bfr[j], acc[i][j], 0, 0, 0);
        }
        __syncthreads();
    }

#pragma unroll
    for (int j = 0; j < 4; ++j) {
        const int n = bn + wn * 64 + j * 16 + l16;
        const float bv = bias[n];
#pragma unroll
        for (int i = 0; i < 4; ++i) {
            const int mb = bm + wm * 64 + i * 16 + quad * 4;
#pragma unroll
            for (int r = 0; r < 4; ++r) {
                float v = acc[i][j][r] + bv;
                if (RELU) v = fmaxf(v, 0.f);
                C[(size_t)(mb + r) * N + n] = (bf16)v;
            }
        }
    }
}

// --------------------------------------------------------------------------
// GEMM-BT + bias + residual + LayerNorm fused.  N = 256 (full row in-block).
// Xout = LN(A@B^T + bias + Xres) * gam + bet.
// 128x256 tile (grid 576), 4 waves 2x2: wave = rows wm*64+64 x cols wn*128.
// LDS: S = As(128x64) | Bs(256x64) XOR-swizzled (48KB); red[128][2].
// In-place Xres==Xout safe: block touches only its own 128 rows.
// --------------------------------------------------------------------------
__global__ __launch_bounds__(256, 2) void gemm_ln_k(
    const bf16* __restrict__ A, const bf16* __restrict__ B,
    const float* __restrict__ bias, const bf16* __restrict__ Xres,
    const float* __restrict__ gam, const float* __restrict__ bet,
    bf16* __restrict__ Xout, int K)
{
    __shared__ __align__(16) bf16 S[24576];   // 48KB: As rows 0-127, Bs rows 128-383
    __shared__ float2 red[128][2];

    const int tid  = threadIdx.x;
    const int lane = tid & 63;
    const int wv   = tid >> 6;
    const int wm   = wv >> 1;          // row-wave 0..1
    const int wn   = wv & 1;           // col-wave 0..1
    const int bm   = blockIdx.x * 128;
    const int quad = lane >> 4;
    const int l16  = lane & 15;

    f32x4 acc[4][8] = {};

    for (int k0 = 0; k0 < K; k0 += 64) {
#pragma unroll
        for (int s = 0; s < 12; ++s) {
            const int L   = s * 256 + tid;     // 0..3071: lds rows 0..383
            const int row = L >> 3;
            const int gch = (L & 7) ^ (row & 7);
            const bf16* g = (row < 128)
                ? A + (size_t)(bm + row) * K + (k0 + gch * 8)
                : B + (size_t)(row - 128) * K + (k0 + gch * 8);
            async_copy16(g, (char*)S + (size_t)L * 16);
        }
        __syncthreads();

#pragma unroll
        for (int kk = 0; kk < 2; ++kk) {
            const int lch = kk * 4 + quad;
            bf16x8 af[4], bfr[8];
#pragma unroll
            for (int i = 0; i < 4; ++i) {
                const int m = wm * 64 + i * 16 + l16;
                af[i] = *(const bf16x8*)((const char*)S + (m * 8 + (lch ^ (m & 7))) * 16);
            }
#pragma unroll
            for (int j = 0; j < 8; ++j) {
                const int n = wn * 128 + j * 16 + l16;
                bfr[j] = *(const bf16x8*)((const char*)S + ((128 + n) * 8 + (lch ^ (n & 7))) * 16);
            }
#pragma unroll
            for (int i = 0; i < 4; ++i)
#pragma unroll
                for (int j = 0; j < 8; ++j)
                    acc[i][j] = __builtin_amdgcn_mfma_f32_16x16x32_bf16(
                        af[i], bfr[j], acc[i][j], 0, 0, 0);
        }
        __syncthreads();
    }

    float bv[8], gv[8], bev[8];
#pragma unroll
    for (int j = 0; j < 8; ++j) {
        const int n = wn * 128 + j * 16 + l16;
        bv[j] = bias[n]; gv[j] = gam[n]; bev[j] = bet[n];
    }

    // v = acc + bias + resid; per-row partials over this wave's 128 cols
#pragma unroll
    for (int i = 0; i < 4; ++i) {
#pragma unroll
        for (int r = 0; r < 4; ++r) {
            const int rl  = wm * 64 + i * 16 + quad * 4 + r;   // 0..127
            const size_t row = (size_t)(bm + rl);
            float s1 = 0.f, s2 = 0.f;
#pragma unroll
            for (int j = 0; j < 8; ++j) {
                const int n = wn * 128 + j * 16 + l16;
                const float v = acc[i][j][r] + bv[j] + (float)Xres[row * 256 + n];
                acc[i][j][r] = v;
                s1 += v; s2 += v * v;
            }
#pragma unroll
            for (int off = 1; off < 16; off <<= 1) {
                s1 += __shfl_xor(s1, off, 64);
                s2 += __shfl_xor(s2, off, 64);
            }
            if (l16 == 0) red[rl][wn] = make_float2(s1, s2);
        }
    }
    __syncthreads();

#pragma unroll
    for (int i = 0; i < 4; ++i) {
#pragma unroll
        for (int r = 0; r < 4; ++r) {
            const int rl = wm * 64 + i * 16 + quad * 4 + r;
            const float2 p0 = red[rl][0], p1 = red[rl][1];
            const float mu  = (p0.x + p1.x) * (1.f / 256.f);
            const float ex2 = (p0.y + p1.y) * (1.f / 256.f);
            const float rstd = rsqrtf(fmaxf(ex2 - mu * mu, 0.f) + 1e-5f);
            const size_t row = (size_t)(bm + rl);
#pragma unroll
            for (int j = 0; j < 8; ++j) {
                const int n = wn * 128 + j * 16 + l16;
                Xout[row * 256 + n] = (bf16)((acc[i][j][r] - mu) * rstd * gv[j] + bev[j]);
            }
        }
    }
}

// --------------------------------------------------------------------------
// attention: per sequence (4 tokens), 8 heads x dh=32, softmax over 4 keys.
// --------------------------------------------------------------------------
__global__ __launch_bounds__(256) void attention_k(const bf16* __restrict__ QKV,
                                                   bf16* __restrict__ SA)
{
    __shared__ float qf[4][4][768];
    __shared__ float sc[4][8][4][4];

    const int tid  = threadIdx.x;
    const int wv   = tid >> 6;
    const int lane = tid & 63;
    const int s    = blockIdx.x * 4 + wv;

    const bf16* base = QKV + (size_t)s * 4 * 768;
    for (int idx = lane; idx < 3072; idx += 64)
        qf[wv][idx / 768][idx % 768] = (float)base[idx];
    __syncthreads();

#pragma unroll
    for (int rep = 0; rep < 2; ++rep) {
        const int t = rep * 64 + lane;
        const int h = t >> 4, i = (t >> 2) & 3, j = t & 3;
        const float* q = &qf[wv][i][h * 32];
        const float* k = &qf[wv][j][256 + h * 32];
        float a = 0.f;
#pragma unroll
        for (int dd = 0; dd < 32; ++dd) {
            const int d = (dd + lane) & 31;
            a += q[d] * k[d];
        }
        sc[wv][h][i][j] = a * 0.17677669529663687f;
    }
    __syncthreads();

    if (lane < 32) {
        const int h = lane >> 2, i = lane & 3;
        float s0 = sc[wv][h][i][0], s1 = sc[wv][h][i][1];
        float s2 = sc[wv][h][i][2], s3 = sc[wv][h][i][3];
        float m = fmaxf(fmaxf(s0, s1), fmaxf(s2, s3));
        float e0 = expf(s0 - m), e1 = expf(s1 - m);
        float e2 = expf(s2 - m), e3 = expf(s3 - m);
        float inv = 1.f / (e0 + e1 + e2 + e3);
        sc[wv][h][i][0] = e0 * inv;
        sc[wv][h][i][1] = e1 * inv;
        sc[wv][h][i][2] = e2 * inv;
        sc[wv][h][i][3] = e3 * inv;
    }
    __syncthreads();

#pragma unroll
    for (int rep = 0; rep < 16; ++rep) {
        const int idx = rep * 64 + lane;
        const int i = idx >> 8, col = idx & 255;
        const int h = col >> 5;
        float a = 0.f;
#pragma unroll
        for (int j = 0; j < 4; ++j)
            a += sc[wv][h][i][j] * qf[wv][j][512 + col];
        SA[(size_t)(s * 4 + i) * 256 + col] = (bf16)a;
    }
}

// --------------------------------------------------------------------------
// out[b][c][hw] = sum_e (mean_cam X[p*4+cam][e]) * Wout[c][e] + bout[c]
// --------------------------------------------------------------------------
__global__ __launch_bounds__(256) void out_proj_k(const bf16* __restrict__ X,
                                                  const float* __restrict__ Wout,
                                                  const float* __restrict__ bout,
                                                  float* __restrict__ out)
{
    __shared__ float fused[16][260];
    const int tid = threadIdx.x;
    const int p0  = blockIdx.x * 16;

#pragma unroll
    for (int it = 0; it < 16; ++it) {
        const int idx = it * 256 + tid;
        const int pix = idx >> 8, e = idx & 255;
        const size_t base = (size_t)(p0 + pix) * 1024 + e;
        const float s = (float)X[base] + (float)X[base + 256] +
                        (float)X[base + 512] + (float)X[base + 768];
        fused[pix][e] = s * 0.25f;
    }
    __syncthreads();

    const int pix = tid & 15;
    const int c0  = tid >> 4;
    const int p   = p0 + pix;
    const int b   = p / 9216;
    const int hw  = p % 9216;
#pragma unroll
    for (int it = 0; it < 4; ++it) {
        const int c = it * 16 + c0;
        const float* w = Wout + c * 256;
        float acc = bout[c];
#pragma unroll 8
        for (int e = 0; e < 256; ++e) acc += fused[pix][e] * w[e];
        out[((size_t)b * 64 + c) * 9216 + hw] = acc;
    }
}

// --------------------------------------------------------------------------
extern "C" void kernel_launch(void* const* d_in, const int* in_sizes, int n_in,
                              void* d_out, int out_size, void* d_ws, size_t ws_size,
                              hipStream_t stream)
{
    const float* features = (const float*)d_in[0];
    const float* Wp   = (const float*)d_in[1];
    const float* bp   = (const float*)d_in[2];
    const float* Wqkv = (const float*)d_in[3];
    const float* bqkv = (const float*)d_in[4];
    const float* Wo   = (const float*)d_in[5];
    const float* bo   = (const float*)d_in[6];
    const float* W1   = (const float*)d_in[7];
    const float* b1   = (const float*)d_in[8];
    const float* W2   = (const float*)d_in[9];
    const float* b2   = (const float*)d_in[10];
    const float* g1   = (const float*)d_in[11];
    const float* be1  = (const float*)d_in[12];
    const float* g2   = (const float*)d_in[13];
    const float* be2  = (const float*)d_in[14];
    const float* Wout = (const float*)d_in[15];
    const float* bout = (const float*)d_in[16];
    float* out = (float*)d_out;

    char* ws = (char*)d_ws;
    bf16* X   = (bf16*)(ws);                    // 73728*256
    bf16* QKV = (bf16*)(ws + 37748736ull);      // 73728*768
    bf16* SAb = (bf16*)(ws + 150994944ull);     // 73728*256
    bf16* Xf  = (bf16*)(ws + 188743680ull);     // 73728*64
    bf16* WpB = (bf16*)(ws + 198180864ull);     // 256*64
    bf16* Wb  = (bf16*)(ws + 226492416ull);     // packed bf16 weights
    bf16* H   = QKV;                            // FFN hidden aliases QKV

    bf16* WqkvB = Wb;                  // 2 x 768*256
    bf16* WoB   = Wb + 393216;         // 2 x 256*256
    bf16* W1B   = Wb + 524288;         // 2 x 1024*256
    bf16* W2B   = Wb + 1048576;        // 2 x 256*1024

    pack_all_k<<<6208, 256, 0, stream>>>(Wqkv, Wo, W1, W2, Wp,
                                         WqkvB, WoB, W1B, W2B, WpB);

    feat_pack_k<<<dim3(144, 8), 256, 0, stream>>>(features, Xf);
    gemm_bt<false><<<dim3(2, 576), 256, 0, stream>>>(Xf, WpB, bp, X, 256, 64);

    for (int l = 0; l < 2; ++l) {
        gemm_bt<false><<<dim3(6, 576), 256, 0, stream>>>(
            X, WqkvB + l * 196608, bqkv + l * 768, QKV, 768, 256);
        attention_k<<<4608, 256, 0, stream>>>(QKV, SAb);
        gemm_ln_k<<<576, 256, 0, stream>>>(
            SAb, WoB + l * 65536, bo + l * 256, X,
            g1 + l * 256, be1 + l * 256, X, 256);
        gemm_bt<true><<<dim3(8, 576), 256, 0, stream>>>(
            X, W1B + l * 262144, b1 + l * 1024, H, 1024, 256);
        gemm_ln_k<<<576, 256, 0, stream>>>(
            H, W2B + l * 262144, b2 + l * 256, X,
            g2 + l * 256, be2 + l * 256, X, 1024);
    }

    out_proj_k<<<1152, 256, 0, stream>>>(X, Wout, bout, out);
}

// Round 5
// 719.761 us; speedup vs baseline: 1.6964x; 1.0529x over previous
//
#include <hip/hip_runtime.h>
#include <cstdint>
#include <cstddef>

// ---------------------------------------------------------------------------
// TransformerMultiViewFusion (MI355X / gfx950), round 5.
//
//  R5 change: fused FFN kernel. R4 showed FFN2 gemm_ln (87us) latency-bound
//  at 24% HBM re-reading the 151MB hidden buffer. ffn_fused_k keeps the
//  64x256 X-tile and the 64x128 T=relu(X@W1c^T) chunk entirely in LDS,
//  accumulating acc2 += T@W2c^T over 8 hidden chunks; epilogue does
//  bias+residual+LayerNorm (red[] aliases the dead stage buffer).
//  LDS 32(Xs)+16(Ts)+32(stage) = 80KB -> 2 blocks/CU. Replaces
//  gemm_bt<relu> + gemm_ln(K=1024): ~420MB HBM/layer -> ~77MB.
//
//  Workspace:
//    X   @ 0          73728*256 bf16   (37,748,736)
//    QKV @ 37748736   73728*768 bf16   (113,246,208)
//    SA  @ 150994944  73728*256 bf16   (37,748,736)
//    Xf  @ 188743680  73728*64  bf16   (9,437,184)
//    WpB @ 198180864  256*64    bf16
//    Wb  @ 226492416  1572864   bf16   (3,145,728)
// ---------------------------------------------------------------------------

typedef __bf16 bf16;
typedef __bf16 bf16x8 __attribute__((ext_vector_type(8)));
typedef float  f32x4  __attribute__((ext_vector_type(4)));

__device__ __forceinline__ void async_copy16(const void* g, void* l)
{
    __builtin_amdgcn_global_load_lds(
        (__attribute__((address_space(1))) void*)g,
        (__attribute__((address_space(3))) void*)l,
        16, 0, 0);
}

// --------------------------------------------------------------------------
// all 5 weight packs in one launch. 1589248 = 6208*256 exactly.
// --------------------------------------------------------------------------
__global__ void pack_all_k(const float* __restrict__ s0, const float* __restrict__ s1,
                           const float* __restrict__ s2, const float* __restrict__ s3,
                           const float* __restrict__ s4,
                           bf16* __restrict__ d0, bf16* __restrict__ d1,
                           bf16* __restrict__ d2, bf16* __restrict__ d3,
                           bf16* __restrict__ d4)
{
    const int i = blockIdx.x * 256 + threadIdx.x;
    if (i < 393216)       d0[i] = (bf16)s0[i];
    else if (i < 524288)  d1[i - 393216] = (bf16)s1[i - 393216];
    else if (i < 1048576) d2[i - 524288] = (bf16)s2[i - 524288];
    else if (i < 1572864) d3[i - 1048576] = (bf16)s3[i - 1048576];
    else                  d4[i - 1572864] = (bf16)s4[i - 1572864];
}

// --------------------------------------------------------------------------
// feat transpose-pack: Xf[t][c] = (bf16)feat[cam][b][c][hw]
// --------------------------------------------------------------------------
__global__ __launch_bounds__(256) void feat_pack_k(const float* __restrict__ feat,
                                                   bf16* __restrict__ Xf)
{
    __shared__ float ft[64][68];

    const int tid  = threadIdx.x;
    const int camb = blockIdx.y;
    const int cam  = camb >> 1;
    const int b    = camb & 1;
    const int hw0  = blockIdx.x * 64;

    const float* fb = feat + (size_t)camb * 64 * 9216 + hw0;
#pragma unroll
    for (int rep = 0; rep < 16; ++rep) {
        const int idx = rep * 256 + tid;
        const int c = idx >> 6, p = idx & 63;
        ft[p][c] = fb[(size_t)c * 9216 + p];
    }
    __syncthreads();

    const int pbase = b * 9216 + hw0;
#pragma unroll
    for (int rep = 0; rep < 2; ++rep) {
        const int idx = rep * 256 + tid;
        const int p = idx >> 3, cc = idx & 7;
        const f32x4 a = *(const f32x4*)(&ft[p][cc * 8]);
        const f32x4 c4 = *(const f32x4*)(&ft[p][cc * 8 + 4]);
        bf16x8 v;
#pragma unroll
        for (int i = 0; i < 4; ++i) { v[i] = (bf16)a[i]; v[4 + i] = (bf16)c4[i]; }
        const size_t t = (size_t)(pbase + p) * 4 + cam;
        *(bf16x8*)(Xf + t * 64 + cc * 8) = v;
    }
}

// --------------------------------------------------------------------------
// GEMM-BT: C[M,N] = A[M,K] @ B[N,K]^T + bias[N], bf16 in/out. 128x128 tile.
// --------------------------------------------------------------------------
template <bool RELU>
__global__ __launch_bounds__(256, 2) void gemm_bt(
    const bf16* __restrict__ A, const bf16* __restrict__ B,
    const float* __restrict__ bias, bf16* __restrict__ C,
    int N, int K)
{
    __shared__ __align__(16) bf16 As[128 * 64];
    __shared__ __align__(16) bf16 Bs[128 * 64];

    const int tid  = threadIdx.x;
    const int lane = tid & 63;
    const int wv   = tid >> 6;
    const int wm   = wv >> 1;
    const int wn   = wv & 1;
    const int bm   = blockIdx.y * 128;
    const int bn   = blockIdx.x * 128;

    const int r8  = lane >> 3;
    const int p8  = lane & 7;
    const int gch = p8 ^ r8;

    const int quad = lane >> 4;
    const int l16  = lane & 15;

    f32x4 acc[4][4] = {};

    for (int k0 = 0; k0 < K; k0 += 64) {
#pragma unroll
        for (int inst = 0; inst < 4; ++inst) {
            const int row = wv * 32 + inst * 8 + r8;
            const bf16* ga = A + (size_t)(bm + row) * K + (k0 + gch * 8);
            const bf16* gb = B + (size_t)(bn + row) * K + (k0 + gch * 8);
            async_copy16(ga, (char*)As + (wv * 4 + inst) * 1024);
            async_copy16(gb, (char*)Bs + (wv * 4 + inst) * 1024);
        }
        __syncthreads();

#pragma unroll
        for (int kk = 0; kk < 2; ++kk) {
            bf16x8 af[4], bfr[4];
            const int lch = kk * 4 + quad;
#pragma unroll
            for (int i = 0; i < 4; ++i) {
                const int m = wm * 64 + i * 16 + l16;
                af[i] = *(const bf16x8*)((const char*)As + (m * 8 + (lch ^ (m & 7))) * 16);
                const int n = wn * 64 + i * 16 + l16;
                bfr[i] = *(const bf16x8*)((const char*)Bs + (n * 8 + (lch ^ (n & 7))) * 16);
            }
#pragma unroll
            for (int i = 0; i < 4; ++i)
#pragma unroll
                for (int j = 0; j < 4; ++j)
                    acc[i][j] = __builtin_amdgcn_mfma_f32_16x16x32_bf16(
                        af[i], bfr[j], acc[i][j], 0, 0, 0);
        }
        __syncthreads();
    }

#pragma unroll
    for (int j = 0; j < 4; ++j) {
        const int n = bn + wn * 64 + j * 16 + l16;
        const float bv = bias[n];
#pragma unroll
        for (int i = 0; i < 4; ++i) {
            const int mb = bm + wm * 64 + i * 16 + quad * 4;
#pragma unroll
            for (int r = 0; r < 4; ++r) {
                float v = acc[i][j][r] + bv;
                if (RELU) v = fmaxf(v, 0.f);
                C[(size_t)(mb + r) * N + n] = (bf16)v;
            }
        }
    }
}

// --------------------------------------------------------------------------
// GEMM-BT + bias + residual + LayerNorm (Wo path, K=256). 128x256 tile.
// --------------------------------------------------------------------------
__global__ __launch_bounds__(256, 2) void gemm_ln_k(
    const bf16* __restrict__ A, const bf16* __restrict__ B,
    const float* __restrict__ bias, const bf16* __restrict__ Xres,
    const float* __restrict__ gam, const float* __restrict__ bet,
    bf16* __restrict__ Xout, int K)
{
    __shared__ __align__(16) bf16 S[24576];
    __shared__ float2 red[128][2];

    const int tid  = threadIdx.x;
    const int lane = tid & 63;
    const int wv   = tid >> 6;
    const int wm   = wv >> 1;
    const int wn   = wv & 1;
    const int bm   = blockIdx.x * 128;
    const int quad = lane >> 4;
    const int l16  = lane & 15;

    f32x4 acc[4][8] = {};

    for (int k0 = 0; k0 < K; k0 += 64) {
#pragma unroll
        for (int s = 0; s < 12; ++s) {
            const int L   = s * 256 + tid;
            const int row = L >> 3;
            const int gch = (L & 7) ^ (row & 7);
            const bf16* g = (row < 128)
                ? A + (size_t)(bm + row) * K + (k0 + gch * 8)
                : B + (size_t)(row - 128) * K + (k0 + gch * 8);
            async_copy16(g, (char*)S + (size_t)L * 16);
        }
        __syncthreads();

#pragma unroll
        for (int kk = 0; kk < 2; ++kk) {
            const int lch = kk * 4 + quad;
            bf16x8 af[4], bfr[8];
#pragma unroll
            for (int i = 0; i < 4; ++i) {
                const int m = wm * 64 + i * 16 + l16;
                af[i] = *(const bf16x8*)((const char*)S + (m * 8 + (lch ^ (m & 7))) * 16);
            }
#pragma unroll
            for (int j = 0; j < 8; ++j) {
                const int n = wn * 128 + j * 16 + l16;
                bfr[j] = *(const bf16x8*)((const char*)S + ((128 + n) * 8 + (lch ^ (n & 7))) * 16);
            }
#pragma unroll
            for (int i = 0; i < 4; ++i)
#pragma unroll
                for (int j = 0; j < 8; ++j)
                    acc[i][j] = __builtin_amdgcn_mfma_f32_16x16x32_bf16(
                        af[i], bfr[j], acc[i][j], 0, 0, 0);
        }
        __syncthreads();
    }

    float bv[8], gv[8], bev[8];
#pragma unroll
    for (int j = 0; j < 8; ++j) {
        const int n = wn * 128 + j * 16 + l16;
        bv[j] = bias[n]; gv[j] = gam[n]; bev[j] = bet[n];
    }

#pragma unroll
    for (int i = 0; i < 4; ++i) {
#pragma unroll
        for (int r = 0; r < 4; ++r) {
            const int rl  = wm * 64 + i * 16 + quad * 4 + r;
            const size_t row = (size_t)(bm + rl);
            float s1 = 0.f, s2 = 0.f;
#pragma unroll
            for (int j = 0; j < 8; ++j) {
                const int n = wn * 128 + j * 16 + l16;
                const float v = acc[i][j][r] + bv[j] + (float)Xres[row * 256 + n];
                acc[i][j][r] = v;
                s1 += v; s2 += v * v;
            }
#pragma unroll
            for (int off = 1; off < 16; off <<= 1) {
                s1 += __shfl_xor(s1, off, 64);
                s2 += __shfl_xor(s2, off, 64);
            }
            if (l16 == 0) red[rl][wn] = make_float2(s1, s2);
        }
    }
    __syncthreads();

#pragma unroll
    for (int i = 0; i < 4; ++i) {
#pragma unroll
        for (int r = 0; r < 4; ++r) {
            const int rl = wm * 64 + i * 16 + quad * 4 + r;
            const float2 p0 = red[rl][0], p1 = red[rl][1];
            const float mu  = (p0.x + p1.x) * (1.f / 256.f);
            const float ex2 = (p0.y + p1.y) * (1.f / 256.f);
            const float rstd = rsqrtf(fmaxf(ex2 - mu * mu, 0.f) + 1e-5f);
            const size_t row = (size_t)(bm + rl);
#pragma unroll
            for (int j = 0; j < 8; ++j) {
                const int n = wn * 128 + j * 16 + l16;
                Xout[row * 256 + n] = (bf16)((acc[i][j][r] - mu) * rstd * gv[j] + bev[j]);
            }
        }
    }
}

// --------------------------------------------------------------------------
// Fused FFN: Xout = LN(X + relu(X@W1^T+b1)@W2^T + b2)*gam + bet, in-place.
// 64-row tile, grid 1152, 4 waves 2x2 (wave: 32 rows x 128 cols for acc2,
// 32 rows x 64 hidden for phase A). 8 hidden chunks of 128.
// LDS: Xs 64x256 (32KB, 32 slots/row) | Ts 64x128 (16KB, 16 slots/row)
//      | stage 32KB (W1c 128x128 or W2c 256x64; red[] aliases it at the end)
// Swizzle: slot = (g & ~7) | ((g ^ row) & 7)  (low-3-bit XOR, self-inverse).
// --------------------------------------------------------------------------
__global__ __launch_bounds__(256, 2) void ffn_fused_k(
    const bf16* __restrict__ X,
    const bf16* __restrict__ W1, const float* __restrict__ b1,
    const bf16* __restrict__ W2, const float* __restrict__ b2,
    const float* __restrict__ gam, const float* __restrict__ bet,
    bf16* __restrict__ Xout)
{
    __shared__ __align__(16) char smem[81920];
    bf16* Xs  = (bf16*)smem;                 // 64 x 256k
    bf16* Ts  = (bf16*)(smem + 32768);       // 64 x 128h
    char* Wst = smem + 49152;                // 32KB stage
    float2 (*red)[2] = (float2 (*)[2])(void*)Wst;

    const int tid  = threadIdx.x;
    const int lane = tid & 63;
    const int wv   = tid >> 6;
    const int wm   = wv >> 1;
    const int wn   = wv & 1;
    const int quad = lane >> 4;
    const int l16  = lane & 15;
    const int bm   = blockIdx.x * 64;

    // load Xs once: 2048 x 16B, 8 insts/thread
#pragma unroll
    for (int it = 0; it < 8; ++it) {
        const int L = it * 256 + tid;
        const int row = L >> 5, slot = L & 31;
        const int gch = (slot & 24) | ((slot ^ row) & 7);
        async_copy16(X + (size_t)(bm + row) * 256 + gch * 8,
                     (char*)Xs + (size_t)L * 16);
    }
    __syncthreads();

    f32x4 acc2[2][8] = {};

    for (int hc = 0; hc < 8; ++hc) {
        f32x4 accA[2][4] = {};

        // ---- phase A: T = relu(Xs @ W1c^T + b1c), K=256 in 2 steps of 128
        for (int k0 = 0; k0 < 256; k0 += 128) {
#pragma unroll
            for (int it = 0; it < 8; ++it) {           // W1c 128r x 128k
                const int L = it * 256 + tid;
                const int row = L >> 4, slot = L & 15;
                const int gch = (slot & 8) | ((slot ^ row) & 7);
                async_copy16(W1 + (size_t)(hc * 128 + row) * 256 + k0 + gch * 8,
                             Wst + (size_t)L * 16);
            }
            __syncthreads();
#pragma unroll
            for (int kk = 0; kk < 4; ++kk) {
                const int lch = kk * 4 + quad;         // 0..15 in staged 128k
                bf16x8 af[2], bfr[4];
#pragma unroll
                for (int i = 0; i < 2; ++i) {
                    const int m  = wm * 32 + i * 16 + l16;
                    const int gc = (k0 >> 3) + lch;    // Xs chunk 0..31
                    const int sl = (gc & 24) | ((gc ^ m) & 7);
                    af[i] = *(const bf16x8*)((const char*)Xs + (m * 32 + sl) * 16);
                }
#pragma unroll
                for (int j = 0; j < 4; ++j) {
                    const int n  = wn * 64 + j * 16 + l16;
                    const int sl = (lch & 8) | ((lch ^ n) & 7);
                    bfr[j] = *(const bf16x8*)(Wst + (n * 16 + sl) * 16);
                }
#pragma unroll
                for (int i = 0; i < 2; ++i)
#pragma unroll
                    for (int j = 0; j < 4; ++j)
                        accA[i][j] = __builtin_amdgcn_mfma_f32_16x16x32_bf16(
                            af[i], bfr[j], accA[i][j], 0, 0, 0);
            }
            __syncthreads();
        }

        // ---- write Ts = relu(accA + b1)
#pragma unroll
        for (int j = 0; j < 4; ++j) {
            const int h  = wn * 64 + j * 16 + l16;
            const float bb = b1[hc * 128 + h];
            const int g  = h >> 3;
#pragma unroll
            for (int i = 0; i < 2; ++i)
#pragma unroll
                for (int r = 0; r < 4; ++r) {
                    const int m  = wm * 32 + i * 16 + quad * 4 + r;
                    const int sl = (g & 8) | ((g ^ m) & 7);
                    const float v = fmaxf(accA[i][j][r] + bb, 0.f);
                    *((bf16*)((char*)Ts + (m * 16 + sl) * 16 + (h & 7) * 2)) = (bf16)v;
                }
        }
        __syncthreads();

        // ---- phase B: acc2 += Ts @ W2c^T, K=128 in 2 steps of 64
        for (int kb = 0; kb < 2; ++kb) {
#pragma unroll
            for (int it = 0; it < 8; ++it) {           // W2c 256r x 64k
                const int L = it * 256 + tid;
                const int row = L >> 3, slot = L & 7;
                const int gch = (slot ^ row) & 7;
                async_copy16(W2 + (size_t)row * 1024 + hc * 128 + kb * 64 + gch * 8,
                             Wst + (size_t)L * 16);
            }
            __syncthreads();
#pragma unroll
            for (int kk = 0; kk < 2; ++kk) {
                const int lch = kb * 8 + kk * 4 + quad; // Ts chunk 0..15
                bf16x8 af[2], bfr[8];
#pragma unroll
                for (int i = 0; i < 2; ++i) {
                    const int m  = wm * 32 + i * 16 + l16;
                    const int sl = (lch & 8) | ((lch ^ m) & 7);
                    af[i] = *(const bf16x8*)((const char*)Ts + (m * 16 + sl) * 16);
                }
#pragma unroll
                for (int j = 0; j < 8; ++j) {
                    const int n  = wn * 128 + j * 16 + l16;
                    const int wl = kk * 4 + quad;       // 0..7 in staged 64k
                    const int sl = (wl ^ n) & 7;
                    bfr[j] = *(const bf16x8*)(Wst + (n * 8 + sl) * 16);
                }
#pragma unroll
                for (int i = 0; i < 2; ++i)
#pragma unroll
                    for (int j = 0; j < 8; ++j)
                        acc2[i][j] = __builtin_amdgcn_mfma_f32_16x16x32_bf16(
                            af[i], bfr[j], acc2[i][j], 0, 0, 0);
            }
            __syncthreads();
        }
    }

    // ---- epilogue: bias + residual + LayerNorm (red aliases dead stage)
    float bv[8], gv[8], bev[8];
#pragma unroll
    for (int j = 0; j < 8; ++j) {
        const int n = wn * 128 + j * 16 + l16;
        bv[j] = b2[n]; gv[j] = gam[n]; bev[j] = bet[n];
    }

#pragma unroll
    for (int i = 0; i < 2; ++i) {
#pragma unroll
        for (int r = 0; r < 4; ++r) {
            const int rl = wm * 32 + i * 16 + quad * 4 + r;
            const size_t row = (size_t)(bm + rl);
            float s1 = 0.f, s2 = 0.f;
#pragma unroll
            for (int j = 0; j < 8; ++j) {
                const int n = wn * 128 + j * 16 + l16;
                const float v = acc2[i][j][r] + bv[j] + (float)X[row * 256 + n];
                acc2[i][j][r] = v;
                s1 += v; s2 += v * v;
            }
#pragma unroll
            for (int off = 1; off < 16; off <<= 1) {
                s1 += __shfl_xor(s1, off, 64);
                s2 += __shfl_xor(s2, off, 64);
            }
            if (l16 == 0) red[rl][wn] = make_float2(s1, s2);
        }
    }
    __syncthreads();

#pragma unroll
    for (int i = 0; i < 2; ++i) {
#pragma unroll
        for (int r = 0; r < 4; ++r) {
            const int rl = wm * 32 + i * 16 + quad * 4 + r;
            const float2 p0 = red[rl][0], p1 = red[rl][1];
            const float mu  = (p0.x + p1.x) * (1.f / 256.f);
            const float ex2 = (p0.y + p1.y) * (1.f / 256.f);
            const float rstd = rsqrtf(fmaxf(ex2 - mu * mu, 0.f) + 1e-5f);
            const size_t row = (size_t)(bm + rl);
#pragma unroll
            for (int j = 0; j < 8; ++j) {
                const int n = wn * 128 + j * 16 + l16;
                Xout[row * 256 + n] = (bf16)((acc2[i][j][r] - mu) * rstd * gv[j] + bev[j]);
            }
        }
    }
}

// --------------------------------------------------------------------------
// attention: per sequence (4 tokens), 8 heads x dh=32, softmax over 4 keys.
// --------------------------------------------------------------------------
__global__ __launch_bounds__(256) void attention_k(const bf16* __restrict__ QKV,
                                                   bf16* __restrict__ SA)
{
    __shared__ float qf[4][4][768];
    __shared__ float sc[4][8][4][4];

    const int tid  = threadIdx.x;
    const int wv   = tid >> 6;
    const int lane = tid & 63;
    const int s    = blockIdx.x * 4 + wv;

    const bf16* base = QKV + (size_t)s * 4 * 768;
    for (int idx = lane; idx < 3072; idx += 64)
        qf[wv][idx / 768][idx % 768] = (float)base[idx];
    __syncthreads();

#pragma unroll
    for (int rep = 0; rep < 2; ++rep) {
        const int t = rep * 64 + lane;
        const int h = t >> 4, i = (t >> 2) & 3, j = t & 3;
        const float* q = &qf[wv][i][h * 32];
        const float* k = &qf[wv][j][256 + h * 32];
        float a = 0.f;
#pragma unroll
        for (int dd = 0; dd < 32; ++dd) {
            const int d = (dd + lane) & 31;
            a += q[d] * k[d];
        }
        sc[wv][h][i][j] = a * 0.17677669529663687f;
    }
    __syncthreads();

    if (lane < 32) {
        const int h = lane >> 2, i = lane & 3;
        float s0 = sc[wv][h][i][0], s1 = sc[wv][h][i][1];
        float s2 = sc[wv][h][i][2], s3 = sc[wv][h][i][3];
        float m = fmaxf(fmaxf(s0, s1), fmaxf(s2, s3));
        float e0 = expf(s0 - m), e1 = expf(s1 - m);
        float e2 = expf(s2 - m), e3 = expf(s3 - m);
        float inv = 1.f / (e0 + e1 + e2 + e3);
        sc[wv][h][i][0] = e0 * inv;
        sc[wv][h][i][1] = e1 * inv;
        sc[wv][h][i][2] = e2 * inv;
        sc[wv][h][i][3] = e3 * inv;
    }
    __syncthreads();

#pragma unroll
    for (int rep = 0; rep < 16; ++rep) {
        const int idx = rep * 64 + lane;
        const int i = idx >> 8, col = idx & 255;
        const int h = col >> 5;
        float a = 0.f;
#pragma unroll
        for (int j = 0; j < 4; ++j)
            a += sc[wv][h][i][j] * qf[wv][j][512 + col];
        SA[(size_t)(s * 4 + i) * 256 + col] = (bf16)a;
    }
}

// --------------------------------------------------------------------------
// out[b][c][hw] = sum_e (mean_cam X[p*4+cam][e]) * Wout[c][e] + bout[c]
// --------------------------------------------------------------------------
__global__ __launch_bounds__(256) void out_proj_k(const bf16* __restrict__ X,
                                                  const float* __restrict__ Wout,
                                                  const float* __restrict__ bout,
                                                  float* __restrict__ out)
{
    __shared__ float fused[16][260];
    const int tid = threadIdx.x;
    const int p0  = blockIdx.x * 16;

#pragma unroll
    for (int it = 0; it < 16; ++it) {
        const int idx = it * 256 + tid;
        const int pix = idx >> 8, e = idx & 255;
        const size_t base = (size_t)(p0 + pix) * 1024 + e;
        const float s = (float)X[base] + (float)X[base + 256] +
                        (float)X[base + 512] + (float)X[base + 768];
        fused[pix][e] = s * 0.25f;
    }
    __syncthreads();

    const int pix = tid & 15;
    const int c0  = tid >> 4;
    const int p   = p0 + pix;
    const int b   = p / 9216;
    const int hw  = p % 9216;
#pragma unroll
    for (int it = 0; it < 4; ++it) {
        const int c = it * 16 + c0;
        const float* w = Wout + c * 256;
        float acc = bout[c];
#pragma unroll 8
        for (int e = 0; e < 256; ++e) acc += fused[pix][e] * w[e];
        out[((size_t)b * 64 + c) * 9216 + hw] = acc;
    }
}

// --------------------------------------------------------------------------
extern "C" void kernel_launch(void* const* d_in, const int* in_sizes, int n_in,
                              void* d_out, int out_size, void* d_ws, size_t ws_size,
                              hipStream_t stream)
{
    const float* features = (const float*)d_in[0];
    const float* Wp   = (const float*)d_in[1];
    const float* bp   = (const float*)d_in[2];
    const float* Wqkv = (const float*)d_in[3];
    const float* bqkv = (const float*)d_in[4];
    const float* Wo   = (const float*)d_in[5];
    const float* bo   = (const float*)d_in[6];
    const float* W1   = (const float*)d_in[7];
    const float* b1   = (const float*)d_in[8];
    const float* W2   = (const float*)d_in[9];
    const float* b2   = (const float*)d_in[10];
    const float* g1   = (const float*)d_in[11];
    const float* be1  = (const float*)d_in[12];
    const float* g2   = (const float*)d_in[13];
    const float* be2  = (const float*)d_in[14];
    const float* Wout = (const float*)d_in[15];
    const float* bout = (const float*)d_in[16];
    float* out = (float*)d_out;

    char* ws = (char*)d_ws;
    bf16* X   = (bf16*)(ws);                    // 73728*256
    bf16* QKV = (bf16*)(ws + 37748736ull);      // 73728*768
    bf16* SAb = (bf16*)(ws + 150994944ull);     // 73728*256
    bf16* Xf  = (bf16*)(ws + 188743680ull);     // 73728*64
    bf16* WpB = (bf16*)(ws + 198180864ull);     // 256*64
    bf16* Wb  = (bf16*)(ws + 226492416ull);     // packed bf16 weights

    bf16* WqkvB = Wb;                  // 2 x 768*256
    bf16* WoB   = Wb + 393216;         // 2 x 256*256
    bf16* W1B   = Wb + 524288;         // 2 x 1024*256
    bf16* W2B   = Wb + 1048576;        // 2 x 256*1024

    pack_all_k<<<6208, 256, 0, stream>>>(Wqkv, Wo, W1, W2, Wp,
                                         WqkvB, WoB, W1B, W2B, WpB);

    feat_pack_k<<<dim3(144, 8), 256, 0, stream>>>(features, Xf);
    gemm_bt<false><<<dim3(2, 576), 256, 0, stream>>>(Xf, WpB, bp, X, 256, 64);

    for (int l = 0; l < 2; ++l) {
        gemm_bt<false><<<dim3(6, 576), 256, 0, stream>>>(
            X, WqkvB + l * 196608, bqkv + l * 768, QKV, 768, 256);
        attention_k<<<4608, 256, 0, stream>>>(QKV, SAb);
        gemm_ln_k<<<576, 256, 0, stream>>>(
            SAb, WoB + l * 65536, bo + l * 256, X,
            g1 + l * 256, be1 + l * 256, X, 256);
        ffn_fused_k<<<1152, 256, 0, stream>>>(
            X, W1B + l * 262144, b1 + l * 1024,
            W2B + l * 262144, b2 + l * 256,
            g2 + l * 256, be2 + l * 256, X);
    }

    out_proj_k<<<1152, 256, 0, stream>>>(X, Wout, bout, out);
}